// Round 11
// baseline (339.938 us; speedup 1.0000x reference)
//
#include <hip/hip_runtime.h>
#include <hip/hip_bf16.h>

typedef __hip_bfloat16 bf16;
typedef __hip_bfloat162 bf162;
typedef __attribute__((ext_vector_type(8))) short short8;
typedef __attribute__((ext_vector_type(4))) float f32x4;
typedef __attribute__((ext_vector_type(16))) float f32x16;

constexpr int kN   = 32768;   // nodes
constexpr int kG   = 128;     // graphs
constexpr int kE   = 262144;  // edges
constexpr int kHA  = 8;       // global attn heads

__device__ __forceinline__ float b2f(bf16 v){ return __bfloat162float(v); }
__device__ __forceinline__ bf16  f2b(float v){ return __float2bfloat16(v); }
__device__ __forceinline__ float b2f_raw(unsigned short u){
  return __uint_as_float((unsigned)u << 16);
}
__device__ __forceinline__ float tanh_fast(float x){
  float e = __expf(2.f*x);
  return 1.f - 2.f/(e+1.f);
}
__device__ __forceinline__ unsigned int cvtpk_bf16(float lo, float hi){
  unsigned int r;
  asm volatile("v_cvt_pk_bf16_f32 %0, %1, %2" : "=v"(r) : "v"(lo), "v"(hi));
  return r;
}
__device__ __forceinline__ void plane_swap(unsigned int &a, unsigned int &b){
  asm volatile("v_permlane32_swap_b32 %0, %1" : "+v"(a), "+v"(b));
}

// ---------------- input dtype detection (bf16 vs fp32 device buffers) ----------------
__global__ void detect_k(const void* xraw, int* flag){
  const bf16* p = (const bf16*)xraw;
  int good = 0;
  for (int i = threadIdx.x; i < 4096; i += 256){
    float v = fabsf(b2f(p[i]));
    if (v > 0.0009765625f && v < 16.f) good++;
  }
  __shared__ int s[256];
  s[threadIdx.x] = good;
  __syncthreads();
  for (int d = 128; d; d >>= 1){
    if (threadIdx.x < d) s[threadIdx.x] += s[threadIdx.x + d];
    __syncthreads();
  }
  if (threadIdx.x == 0) *flag = (s[0] < 3500) ? 1 : 0;
}

// ---------------- import (params to fp32 ws) ----------------
struct ImpEnt { const void* src; void* dst; int n; };
struct ImpArgs { ImpEnt e[23]; };
__global__ __launch_bounds__(256) void import_k(ImpArgs a, const int* __restrict__ flag){
  ImpEnt en = a.e[blockIdx.y];
  const bool f32 = (*flag != 0);
  for (int i = blockIdx.x*256 + threadIdx.x; i < en.n; i += gridDim.x*256){
    float v = f32 ? ((const float*)en.src)[i] : b2f(((const bf16*)en.src)[i]);
    ((float*)en.dst)[i] = v;
  }
}

// ---------------- weight repack to MFMA-B fragment layout ----------------
__global__ __launch_bounds__(256) void repack5_k(const float* __restrict__ W0,
    const float* __restrict__ W1p, const float* __restrict__ W2p,
    const float* __restrict__ W3p, const float* __restrict__ W4p,
    bf16* __restrict__ dst){
  int idx = blockIdx.x*256 + threadIdx.x;
  const float* Ws[5] = {W0, W1p, W2p, W3p, W4p};
  int o = idx >> 14;
  int rem = idx & 16383;
  int j = rem & 7, l = (rem >> 3) & 63, t = rem >> 9;
  int ks = t >> 3, cb = t & 7;
  int k = ks*32 + (l>>4)*8 + j;
  int c = cb*16 + (l&15);
  dst[idx] = f2b(Ws[o][k*128 + c]);
}

// mode 0: plain; mode 1: perm'd cols p(c)=(c&15)*8+(c>>4); mode 2: We 32x8 padded to 16 cols
struct RepEnt { const float* src; bf16* dst; int total; int ncb_log; int dout; int mode; };
__global__ __launch_bounds__(256) void repack_k(RepEnt e0, RepEnt e1, RepEnt e2,
                                                RepEnt e3, RepEnt e4){
  RepEnt en = (blockIdx.y == 0) ? e0 : (blockIdx.y == 1) ? e1 :
              (blockIdx.y == 2) ? e2 : (blockIdx.y == 3) ? e3 : e4;
  int idx = blockIdx.x*256 + threadIdx.x;
  if (idx >= en.total) return;
  int j = idx & 7, l = (idx >> 3) & 63, t = idx >> 9;
  if (en.mode == 2){
    int k = (l>>4)*8 + j;
    int c = l & 15;
    en.dst[idx] = (c < 8) ? f2b(en.src[k*8 + c]) : f2b(0.f);
    return;
  }
  int ncbm = (1 << en.ncb_log) - 1;
  int ks = t >> en.ncb_log, cb = t & ncbm;
  int k = ks*32 + (l>>4)*8 + j;
  int c = cb*16 + (l&15);
  if (en.mode == 1) c = ((c & 15) << 3) | (c >> 4);
  en.dst[idx] = f2b(en.src[k*en.dout + c]);
}

// ---------------- fused 5-way projection GEMM (reads raw x, dtype-flag branch) -------
__global__ __launch_bounds__(256) void gemm5_k(const void* __restrict__ xraw,
    const int* __restrict__ flag,
    const bf16* __restrict__ Wrep, const float* __restrict__ bias5,
    bf16* __restrict__ proj5){
  const int tid = threadIdx.x;
  const int wid = tid >> 6, l = tid & 63;
  const long r0 = (long)blockIdx.x*64 + wid*16;
  const bool f32 = (*flag != 0);
  short8 af[4];
  if (f32){
    const float* fr = (const float*)xraw + (r0 + (l&15))*128;
    #pragma unroll
    for (int ks=0; ks<4; ks++){
      float4 a = *(const float4*)(fr + ks*32 + (l>>4)*8);
      float4 b = *(const float4*)(fr + ks*32 + (l>>4)*8 + 4);
      union{ unsigned int u[4]; short8 s; } c;
      c.u[0]=cvtpk_bf16(a.x,a.y); c.u[1]=cvtpk_bf16(a.z,a.w);
      c.u[2]=cvtpk_bf16(b.x,b.y); c.u[3]=cvtpk_bf16(b.z,b.w);
      af[ks] = c.s;
    }
  } else {
    const short* Arow = (const short*)xraw + (r0 + (l&15))*128;
    #pragma unroll
    for (int ks=0; ks<4; ks++)
      af[ks] = *(const short8*)(Arow + ks*32 + (l>>4)*8);
  }
  const short8* Wp = (const short8*)Wrep;
  const int cc = l & 15, rr = (l >> 4) * 4;
  #pragma unroll 1
  for (int o=0; o<5; o++){
    f32x4 acc[8];
    #pragma unroll
    for (int cb=0; cb<8; cb++) acc[cb] = (f32x4){0.f,0.f,0.f,0.f};
    #pragma unroll
    for (int ks=0; ks<4; ks++){
      #pragma unroll
      for (int cb=0; cb<8; cb++){
        short8 bf = Wp[(o*32 + ks*8 + cb)*64 + l];
        acc[cb] = __builtin_amdgcn_mfma_f32_16x16x32_bf16(af[ks], bf, acc[cb], 0,0,0);
      }
    }
    bf16* outb = proj5 + (long)o*kN*128;
    #pragma unroll
    for (int cb=0; cb<8; cb++){
      float bb = bias5[o*128 + cb*16 + cc];
      #pragma unroll
      for (int r=0; r<4; r++){
        long row = r0 + rr + r;
        outb[row*128 + cb*16 + cc] = f2b(acc[cb][r] + bb);
      }
    }
  }
}

// ---------------- generic MFMA GEMM ----------------
template<int DIN, int DOUT, int EPI>
__global__ __launch_bounds__(256) void gemm_mfma_k(const bf16* __restrict__ A,
    const bf16* __restrict__ Wrep, const float* __restrict__ bias,
    bf16* __restrict__ C){
  constexpr int KS = DIN/32, NCB = DOUT/16;
  const int tid = threadIdx.x;
  const int wid = tid >> 6, l = tid & 63;
  const long r0 = (long)blockIdx.x*64 + wid*16;
  const short* Arow = (const short*)(A + (r0 + (l&15))*(long)DIN);
  short8 af[KS];
  #pragma unroll
  for (int ks=0; ks<KS; ks++)
    af[ks] = *(const short8*)(Arow + ks*32 + (l>>4)*8);
  f32x4 acc[NCB];
  #pragma unroll
  for (int cb=0; cb<NCB; cb++) acc[cb] = (f32x4){0.f,0.f,0.f,0.f};
  const short8* Wp = (const short8*)Wrep;
  #pragma unroll
  for (int ks=0; ks<KS; ks++){
    #pragma unroll
    for (int cb=0; cb<NCB; cb++){
      short8 bf = Wp[(ks*NCB + cb)*64 + l];
      acc[cb] = __builtin_amdgcn_mfma_f32_16x16x32_bf16(af[ks], bf, acc[cb], 0,0,0);
    }
  }
  const int cc = l & 15, rr = (l >> 4) * 4;
  #pragma unroll
  for (int cb=0; cb<NCB; cb++){
    float bb = bias[cb*16 + cc];
    #pragma unroll
    for (int r=0; r<4; r++){
      long row = r0 + rr + r;
      float v = acc[cb][r] + bb;
      if (EPI == 2) v = 0.5f*v*(1.f + erff(v*0.70710678118654752f));
      C[row*DOUT + cb*16 + cc] = f2b(v);
    }
  }
}

// ---------------- CSR build (by dst, and by src for attention) ----------------
__global__ void hist_k(const int* __restrict__ idxA, int* __restrict__ cnt){
  int e = blockIdx.x*256 + threadIdx.x;
  if (e < kE) atomicAdd(&cnt[idxA[e]], 1);
}

__global__ __launch_bounds__(1024) void scan_k(const int* __restrict__ cnt, int* __restrict__ rowptr){
  __shared__ int part[1024];
  const int t = threadIdx.x;
  const int base = t*32;
  int s = 0;
  #pragma unroll
  for (int i=0;i<32;i++) s += cnt[base+i];
  part[t] = s;
  __syncthreads();
  for (int d=1; d<1024; d<<=1){
    int v = (t>=d) ? part[t-d] : 0;
    __syncthreads();
    part[t] += v;
    __syncthreads();
  }
  int run = (t==0) ? 0 : part[t-1];
  for (int i=0;i<32;i++){ rowptr[base+i] = run; run += cnt[base+i]; }
  if (t == 1023) rowptr[kN] = run;
}

__global__ void scatter_k(const int* __restrict__ dstA, const int* __restrict__ rowptr,
                          int* __restrict__ cursor, int* __restrict__ eidx,
                          int* __restrict__ pos_t){
  int e = blockIdx.x*256 + threadIdx.x;
  if (e < kE){
    int d = dstA[e];
    int p = atomicAdd(&cursor[d], 1);
    int t = rowptr[d]+p;
    eidx[t] = e;
    pos_t[e] = t;
  }
}

// src-CSR: packed[u] = (dst&255)<<24 | pos_t[e]  (dst-order index for ebuf_t gather)
__global__ void scatter2_k(const int* __restrict__ srcA, const int* __restrict__ dstA,
                           const int* __restrict__ srcptr, int* __restrict__ cursor2,
                           const int* __restrict__ pos_t, unsigned int* __restrict__ packed){
  int e = blockIdx.x*256 + threadIdx.x;
  if (e < kE){
    int s = srcA[e];
    int p = atomicAdd(&cursor2[s], 1);
    packed[srcptr[s]+p] = ((unsigned int)(dstA[e] & 255) << 24) | (unsigned int)pos_t[e];
  }
}

// ---------------- edge3 v4: CSR-ordered, MFMA edge GEMM (perm'd cols) + MFMA eb,
// direct coalesced epilogue gather (no LDS stage), graph-locality XCD swizzle.
__global__ __launch_bounds__(256) void edge3_k(const void* __restrict__ ea_raw,
    const int* __restrict__ flag,
    const int* __restrict__ eidx, const int* __restrict__ srcA,
    const int* __restrict__ dstA,
    const bf16* __restrict__ xs, const bf16* __restrict__ xd,
    const bf16* __restrict__ WeR_edge,     // perm'd: out col c -> orig ch (c&15)*8+(c>>4)
    const bf16* __restrict__ WeR_eb,       // We 32x8 padded to 16 cols, frag layout
    const float* __restrict__ att_f, const float* __restrict__ be_f,
    float* __restrict__ expal_t, float* __restrict__ ebuf_t,
    int* __restrict__ src_t){
  __shared__ int sEid[64], sSrc[64], sDst[64];
  __shared__ float sAlphaF[64*4];
  const int tid = threadIdx.x;
  const int w = tid >> 6, l = tid & 63;
  const int p = blockIdx.x;
  const int bid = (p & 7) * (gridDim.x >> 3) + (p >> 3);
  const long t0 = (long)bid * 64;
  const bool f32 = (*flag != 0);

  if (tid < 64){
    int e = eidx[t0 + tid];
    int s = srcA[e], d = dstA[e];
    sEid[tid] = e; sSrc[tid] = s; sDst[tid] = d;
    src_t[t0 + tid] = s;
  }
  __syncthreads();

  short8 af;
  {
    long eoff = (long)sEid[w*16 + (l&15)]*32 + (l>>4)*8;
    if (f32){
      const float* er = (const float*)ea_raw + eoff;
      float4 a = *(const float4*)er;
      float4 b = *(const float4*)(er + 4);
      union{ unsigned int u[4]; short8 s; } c;
      c.u[0]=cvtpk_bf16(a.x,a.y); c.u[1]=cvtpk_bf16(a.z,a.w);
      c.u[2]=cvtpk_bf16(b.x,b.y); c.u[3]=cvtpk_bf16(b.z,b.w);
      af = c.s;
    } else {
      af = *(const short8*)((const short*)ea_raw + eoff);
    }
  }

  f32x4 acc[8], acc_eb;
  #pragma unroll
  for (int cb=0; cb<8; cb++){
    short8 wb = *(const short8*)((const short*)WeR_edge + (cb*64 + l)*8);
    acc[cb] = __builtin_amdgcn_mfma_f32_16x16x32_bf16(af, wb,
                (f32x4){0.f,0.f,0.f,0.f}, 0,0,0);
  }
  {
    short8 wbe = *(const short8*)((const short*)WeR_eb + l*8);
    acc_eb = __builtin_amdgcn_mfma_f32_16x16x32_bf16(af, wbe,
                (f32x4){0.f,0.f,0.f,0.f}, 0,0,0);
  }

  const int c15 = l & 15;
  const float be_v = be_f[c15 & 7];
  float4 at0 = *(const float4*)(att_f + c15*8);
  float4 at1 = *(const float4*)(att_f + c15*8 + 4);
  const float attv[8] = {at0.x,at0.y,at0.z,at0.w, at1.x,at1.y,at1.z,at1.w};
  union U8 { short8 s8; unsigned short u[8]; };
  U8 gx[4], gd[4];
  #pragma unroll
  for (int r=0; r<4; r++){
    int e_l = w*16 + (l>>4)*4 + r;
    gx[r].s8 = *(const short8*)((const short*)xs + (long)sSrc[e_l]*128 + c15*8);
    gd[r].s8 = *(const short8*)((const short*)xd + (long)sDst[e_l]*128 + c15*8);
  }
  #pragma unroll
  for (int r=0; r<4; r++){
    int e_l = w*16 + (l>>4)*4 + r;
    float hsum = 0.f;
    #pragma unroll
    for (int cb=0; cb<8; cb++){
      float v = acc[cb][r] + b2f_raw(gx[r].u[cb]) + b2f_raw(gd[r].u[cb]);
      hsum += tanh_fast(v) * attv[cb];
    }
    hsum += __shfl_xor(hsum,1);
    hsum += __shfl_xor(hsum,2);
    if ((c15 & 3) == 0) sAlphaF[e_l*4 + (c15>>2)] = __expf(hsum);
    if (c15 < 8) ebuf_t[(long)c15*kE + t0 + e_l] = acc_eb[r] + be_v;
  }
  __syncthreads();
  if (tid < 64)
    *(float4*)&expal_t[(t0 + tid)*4] = *(float4*)&sAlphaF[tid*4];
}

// ---------------- GAT aggregate: 32 lanes/node, single pass, graph-locality swizzle --
__global__ __launch_bounds__(256) void gat_agg_k(const float* __restrict__ expal,
    const int* __restrict__ rowptr, const int* __restrict__ src_t,
    const bf16* __restrict__ xs, const float* __restrict__ gatb_f,
    bf16* __restrict__ h_local){
  const int tid = threadIdx.x;
  const int grp = tid >> 5;
  const int l   = tid & 31;
  const int p   = blockIdx.x;
  const int bid = (p & 7) * (gridDim.x >> 3) + (p >> 3);
  const int v   = bid*8 + grp;
  const int c0  = l*4;
  const int head = l >> 3;
  const int beg = rowptr[v], end = rowptr[v+1];
  float den = 0.f, o0 = 0.f, o1 = 0.f, o2 = 0.f, o3 = 0.f;
  const unsigned short* xsu = (const unsigned short*)xs;
  for (int t = beg; t < end; t++){
    float w = expal[(long)t*4 + head];
    long s = src_t[t];
    ushort4 a = *(const ushort4*)(xsu + s*128 + c0);
    den += w;
    o0 += w*b2f_raw(a.x); o1 += w*b2f_raw(a.y);
    o2 += w*b2f_raw(a.z); o3 += w*b2f_raw(a.w);
  }
  float inv = 1.f/(den + 1e-16f);
  float4 gb = *(const float4*)(gatb_f + c0);
  unsigned int lo = cvtpk_bf16(o0*inv + gb.x, o1*inv + gb.y);
  unsigned int hi = cvtpk_bf16(o2*inv + gb.z, o3*inv + gb.w);
  *(uint2*)&((unsigned short*)h_local)[(long)v*128 + c0] = (uint2){lo, hi};
}

// ---------------- attn3: barrier-free MFMA flash attention with register bias --------
// block=(g,h), 8 waves, wave = 32-query tile. Bias from src-CSR scanned into badd[16]
// registers (static indices). No max-subtraction (scores+bias bounded ~±14).
__global__ __launch_bounds__(512, 6) void attn3_k(const bf16* __restrict__ qb,
    const bf16* __restrict__ kb, const bf16* __restrict__ vb,
    const float* __restrict__ ebuf_t, const int* __restrict__ srcptr,
    const unsigned int* __restrict__ packed, bf16* __restrict__ hattn){
  __shared__ short Vf[16*64*8];     // 16 KB only
  const int bid = blockIdx.x;
  const int h = (bid >> 3) >> 4;
  const int g = (((bid >> 3) & 15) << 3) | (bid & 7);
  const int tid = threadIdx.x;
  const int w = tid >> 6, l = tid & 63;
  const int q31 = l & 31, hi = l >> 5;
  const int nbase = g << 8;

  for (int s2 = tid; s2 < 1024; s2 += 512){
    int f = s2 >> 6, ll = s2 & 63;
    int keyb = (f>>1)*32 + (f&1)*16 + ((ll>>5)*8);
    int d = ll & 15;
    short tmp[8];
    #pragma unroll
    for (int j=0;j<8;j++)
      tmp[j] = ((const short*)vb)[((long)(nbase + keyb + j))*128 + h*16 + d];
    *(short8*)&Vf[s2*8] = *(short8*)tmp;
  }
  short8 qf = *(const short8*)((const short*)qb + ((long)(nbase + w*32 + q31))*128 + h*16 + hi*8);
  const int q = nbase + w*32 + q31;
  const int u0 = srcptr[q], u1 = srcptr[q+1];
  const float* ebh = ebuf_t + (long)h*kE;
  __syncthreads();

  float lsum = 0.f;
  f32x16 oacc = {0.f,0.f,0.f,0.f,0.f,0.f,0.f,0.f,0.f,0.f,0.f,0.f,0.f,0.f,0.f,0.f};
  short8 kf = *(const short8*)((const short*)kb + ((long)(nbase + q31))*128 + h*16 + hi*8);
  #pragma unroll 1
  for (int kt = 0; kt < 8; kt++){
    short8 kcur = kf;
    if (kt < 7)
      kf = *(const short8*)((const short*)kb +
            ((long)(nbase + (kt+1)*32 + q31))*128 + h*16 + hi*8);
    f32x16 acc = {0.f,0.f,0.f,0.f,0.f,0.f,0.f,0.f,0.f,0.f,0.f,0.f,0.f,0.f,0.f,0.f};
    acc = __builtin_amdgcn_mfma_f32_32x32x16_bf16(kcur, qf, acc, 0, 0, 0);
    // bias for this tile from this query's edge list (register accumulate)
    float badd[16];
    #pragma unroll
    for (int rr=0;rr<16;rr++) badd[rr] = 0.f;
    for (int u = u0; u < u1; ++u){
      unsigned int v = packed[u];
      unsigned int key = v >> 24;
      if ((int)(key >> 5) == kt && (int)((key >> 2) & 1) == hi){
        int re = (int)(key & 3) | ((int)((key & 31) >> 3) << 2);
        float b = ebh[v & 0xFFFFFFu];
        #pragma unroll
        for (int rr=0;rr<16;rr++) badd[rr] += (rr == re) ? b : 0.f;
      }
    }
    float s[16];
    float psum = 0.f;
    #pragma unroll
    for (int r=0;r<16;r++){
      s[r] = __expf(fmaf(acc[r], 0.25f, badd[r]));
      psum += s[r];
    }
    lsum += psum;
    unsigned int a  = cvtpk_bf16(s[0],  s[1]);
    unsigned int b  = cvtpk_bf16(s[2],  s[3]);
    unsigned int c  = cvtpk_bf16(s[4],  s[5]);
    unsigned int d  = cvtpk_bf16(s[6],  s[7]);
    unsigned int e  = cvtpk_bf16(s[8],  s[9]);
    unsigned int f  = cvtpk_bf16(s[10], s[11]);
    unsigned int g2 = cvtpk_bf16(s[12], s[13]);
    unsigned int h2 = cvtpk_bf16(s[14], s[15]);
    plane_swap(a, c); plane_swap(b, d); plane_swap(e, g2); plane_swap(f, h2);
    union { unsigned int u[4]; short8 s8; } A1, A2;
    A1.u[0]=a; A1.u[1]=b; A1.u[2]=c; A1.u[3]=d;
    A2.u[0]=e; A2.u[1]=f; A2.u[2]=g2; A2.u[3]=h2;
    short8 v1 = *(short8*)&Vf[((kt*2+0)*64 + l)*8];
    short8 v2 = *(short8*)&Vf[((kt*2+1)*64 + l)*8];
    oacc = __builtin_amdgcn_mfma_f32_32x32x16_bf16(A1.s8, v1, oacc, 0,0,0);
    oacc = __builtin_amdgcn_mfma_f32_32x32x16_bf16(A2.s8, v2, oacc, 0,0,0);
  }
  lsum += __shfl_xor(lsum, 32);
  float linv = 1.f / lsum;
  #pragma unroll
  for (int r=0;r<16;r++){
    int qrow = (r&3) + 8*(r>>2) + 4*hi;
    float li = __shfl(linv, qrow);
    float ov = oacc[r]*li;
    if (q31 < 16)
      hattn[((long)(nbase + w*32 + qrow))*128 + h*16 + q31] = f2b(ov);
  }
}

// ---------------- residual add + LayerNorm ----------------
__global__ __launch_bounds__(256) void combine_ln_k(const void* __restrict__ a,
    const bf16* __restrict__ b, const bf16* __restrict__ c3,
    const float* __restrict__ g, const float* __restrict__ bb,
    void* __restrict__ outp, const int* __restrict__ flag,
    int a_raw, int is_final){
  const int tid = threadIdx.x;
  const int lane = tid & 63;
  const long row = (long)blockIdx.x*4 + (tid>>6);
  const long base = row*128;
  float a0, a1;
  if (a_raw && (*flag)){
    const float* ap = (const float*)a;
    a0 = ap[base+lane]; a1 = ap[base+lane+64];
  } else {
    const bf16* ap = (const bf16*)a;
    a0 = b2f(ap[base+lane]); a1 = b2f(ap[base+lane+64]);
  }
  float v0 = a0 + b2f(b[base+lane]);
  float v1 = a1 + b2f(b[base+lane+64]);
  if (c3){ v0 += b2f(c3[base+lane]); v1 += b2f(c3[base+lane+64]); }
  float s = v0 + v1;
  #pragma unroll
  for (int o=1; o<64; o<<=1) s += __shfl_xor(s, o);
  float mean = s * (1.f/128.f);
  float d0 = v0 - mean, d1 = v1 - mean;
  float q = d0*d0 + d1*d1;
  #pragma unroll
  for (int o=1; o<64; o<<=1) q += __shfl_xor(q, o);
  float r = rsqrtf(q*(1.f/128.f) + 1e-5f);
  float r0v = d0*r*g[lane]    + bb[lane];
  float r1v = d1*r*g[lane+64] + bb[lane+64];
  if (is_final && (*flag)){
    float* o = (float*)outp;
    o[base+lane]    = r0v;
    o[base+lane+64] = r1v;
  } else {
    bf16* o = (bf16*)outp;
    o[base+lane]    = f2b(r0v);
    o[base+lane+64] = f2b(r1v);
  }
}

// =====================================================================================
extern "C" void kernel_launch(void* const* d_in, const int* in_sizes, int n_in,
                              void* d_out, int out_size, void* d_ws, size_t ws_size,
                              hipStream_t stream){
  const void* x_raw   = d_in[0];
  const void* ea_raw  = d_in[1];
  const int*  ei      = (const int*)d_in[25];
  const int* srcA = ei;
  const int* dstA = ei + kE;

  char* ws = (char*)d_ws;
  size_t off = 0;
  auto alloc = [&](size_t bytes)->void*{
    void* p = ws + off;
    off = (off + bytes + 255) & ~(size_t)255;
    return p;
  };
  int*   flag    = (int*)alloc(4);
  float* Wsrc_f  = (float*)alloc(16384*4);
  float* Wdst_f  = (float*)alloc(16384*4);
  float* Wedge_f = (float*)alloc(4096*4);
  float* att_f   = (float*)alloc(128*4);
  float* gatb_f  = (float*)alloc(128*4);
  float* Wq_f    = (float*)alloc(16384*4);
  float* Wk_f    = (float*)alloc(16384*4);
  float* Wv_f    = (float*)alloc(16384*4);
  float* Wo_f    = (float*)alloc(16384*4);
  float* bo_f    = (float*)alloc(128*4);
  float* We_f    = (float*)alloc(256*4);
  float* be_f    = (float*)alloc(8*4);
  float* ln1g_f  = (float*)alloc(128*4);
  float* ln1b_f  = (float*)alloc(128*4);
  float* W1_f    = (float*)alloc(32768*4);
  float* b1_f    = (float*)alloc(256*4);
  float* W2_f    = (float*)alloc(32768*4);
  float* b2_f    = (float*)alloc(128*4);
  float* ln2g_f  = (float*)alloc(128*4);
  float* ln2b_f  = (float*)alloc(128*4);
  float* bias5   = (float*)alloc(640*4);
  bf16*  Wrep5   = (bf16*)alloc((size_t)5*16384*2);
  bf16*  WoR     = (bf16*)alloc((size_t)16384*2);
  bf16*  W1R     = (bf16*)alloc((size_t)32768*2);
  bf16*  W2R     = (bf16*)alloc((size_t)32768*2);
  bf16*  WeR     = (bf16*)alloc((size_t)4096*2);
  bf16*  WeRb    = (bf16*)alloc((size_t)512*2);
  bf16*  proj5   = (bf16*)alloc((size_t)5*kN*128*2);
  bf16* xs   = proj5;
  bf16* xd   = proj5 + (size_t)kN*128;
  bf16* qb   = proj5 + (size_t)2*kN*128;
  bf16* kbuf = proj5 + (size_t)3*kN*128;
  bf16* vbuf = proj5 + (size_t)4*kN*128;
  int* cnt        = (int*)alloc((size_t)4*kN*4);   // cnt | cursor | cnt2 | cursor2
  int* cursor     = cnt + kN;
  int* cnt2       = cnt + 2*kN;
  int* cursor2    = cnt + 3*kN;
  int* rowptr     = (int*)alloc((size_t)(kN+1)*4);
  int* srcptr     = (int*)alloc((size_t)(kN+1)*4);
  int* eidx       = (int*)alloc((size_t)kE*4);
  int* pos_t      = (int*)alloc((size_t)kE*4);
  unsigned int* packed = (unsigned int*)alloc((size_t)kE*4);
  float* ebuf_t   = (float*)alloc((size_t)8*kE*4);
  float* expal_t  = (float*)alloc((size_t)kE*4*4);
  int*   src_t    = (int*)alloc((size_t)kE*4);
  bf16* h_local   = (bf16*)alloc((size_t)kN*128*2);
  bf16* hattn_pre = (bf16*)alloc((size_t)kN*128*2);
  bf16* h_attn    = (bf16*)alloc((size_t)kN*128*2);
  bf16* hbuf      = (bf16*)alloc((size_t)kN*128*2);
  bf16* tbuf      = (bf16*)alloc((size_t)kN*256*2);
  bf16* f2buf     = (bf16*)alloc((size_t)kN*128*2);
  (void)ws_size; (void)in_sizes; (void)n_in; (void)out_size;

  dim3 b256(256);

  detect_k<<<1, b256, 0, stream>>>(x_raw, flag);
  hipMemsetAsync(bias5, 0, 256*4, stream);
  hipMemsetAsync(cnt, 0, (size_t)4*kN*4, stream);

  // CSR by dst (edge3/gat order) and CSR by src (attn bias)
  hist_k<<<kE/256, b256, 0, stream>>>(dstA, cnt);
  scan_k<<<1, 1024, 0, stream>>>(cnt, rowptr);
  scatter_k<<<kE/256, b256, 0, stream>>>(dstA, rowptr, cursor, eidx, pos_t);
  hist_k<<<kE/256, b256, 0, stream>>>(srcA, cnt2);
  scan_k<<<1, 1024, 0, stream>>>(cnt2, srcptr);
  scatter2_k<<<kE/256, b256, 0, stream>>>(srcA, dstA, srcptr, cursor2, pos_t, packed);

  ImpArgs ia;
  const void* srcs[23] = {d_in[2], d_in[3], d_in[4], d_in[5], d_in[6],
                          d_in[7], d_in[8], d_in[9], d_in[10], d_in[11], d_in[12],
                          d_in[13], d_in[14], d_in[15], d_in[16], d_in[17], d_in[18],
                          d_in[19], d_in[20], d_in[21], d_in[22], d_in[23], d_in[24]};
  void* dsts[23] = {Wsrc_f, Wdst_f, Wedge_f, att_f, gatb_f,
                    Wq_f, bias5+256, Wk_f, bias5+384, Wv_f, bias5+512,
                    Wo_f, bo_f, We_f, be_f, ln1g_f, ln1b_f,
                    W1_f, b1_f, W2_f, b2_f, ln2g_f, ln2b_f};
  int ns[23] = {16384, 16384, 4096, 128, 128,
                16384, 128, 16384, 128, 16384, 128,
                16384, 128, 256, 8, 128, 128,
                32768, 256, 32768, 128, 128, 128};
  for (int i=0;i<23;i++){ ia.e[i].src=srcs[i]; ia.e[i].dst=dsts[i]; ia.e[i].n=ns[i]; }
  import_k<<<dim3(64,23), b256, 0, stream>>>(ia, flag);

  repack5_k<<<(5*16384)/256, b256, 0, stream>>>(Wsrc_f, Wdst_f, Wq_f, Wk_f, Wv_f, Wrep5);
  RepEnt ro{Wo_f, WoR, 16384, 3, 128, 0};
  RepEnt r1{W1_f, W1R, 32768, 4, 256, 0};
  RepEnt r2{W2_f, W2R, 32768, 3, 128, 0};
  RepEnt re{Wedge_f, WeR, 4096, 3, 128, 1};
  RepEnt rb{We_f, WeRb, 512, 0, 8, 2};
  repack_k<<<dim3(128,5), b256, 0, stream>>>(ro, r1, r2, re, rb);

  gemm5_k<<<kN/64, b256, 0, stream>>>(x_raw, flag, Wrep5, bias5, proj5);

  edge3_k<<<kE/64, b256, 0, stream>>>(ea_raw, flag, eidx, srcA, dstA, xs, xd,
                                      WeR, WeRb, att_f, be_f,
                                      expal_t, ebuf_t, src_t);

  gat_agg_k<<<kN/8, b256, 0, stream>>>(expal_t, rowptr, src_t, xs, gatb_f, h_local);

  attn3_k<<<kG*kHA, dim3(512), 0, stream>>>(qb, kbuf, vbuf, ebuf_t, srcptr, packed, hattn_pre);
  gemm_mfma_k<128,128,1><<<kN/64, b256, 0, stream>>>(hattn_pre, WoR, bo_f, h_attn);

  combine_ln_k<<<kN/4, b256, 0, stream>>>(x_raw, h_local, h_attn, ln1g_f, ln1b_f,
                                          hbuf, flag, 1, 0);

  gemm_mfma_k<128,256,2><<<kN/64, b256, 0, stream>>>(hbuf, W1R, b1_f, tbuf);
  gemm_mfma_k<256,128,1><<<kN/64, b256, 0, stream>>>(tbuf, W2R, b2_f, f2buf);

  combine_ln_k<<<kN/4, b256, 0, stream>>>(hbuf, f2buf, nullptr, ln2g_f, ln2b_f,
                                          d_out, flag, 0, 1);
}

// Round 12
// 230.452 us; speedup vs baseline: 1.4751x; 1.4751x over previous
//
#include <hip/hip_runtime.h>
#include <hip/hip_bf16.h>

typedef __hip_bfloat16 bf16;
typedef __hip_bfloat162 bf162;
typedef __attribute__((ext_vector_type(8))) short short8;
typedef __attribute__((ext_vector_type(4))) float f32x4;
typedef __attribute__((ext_vector_type(16))) float f32x16;

constexpr int kN   = 32768;   // nodes
constexpr int kG   = 128;     // graphs
constexpr int kE   = 262144;  // edges
constexpr int kHA  = 8;       // global attn heads

__device__ __forceinline__ float b2f(bf16 v){ return __bfloat162float(v); }
__device__ __forceinline__ bf16  f2b(float v){ return __float2bfloat16(v); }
__device__ __forceinline__ float b2f_raw(unsigned short u){
  return __uint_as_float((unsigned)u << 16);
}
__device__ __forceinline__ float tanh_fast(float x){
  float e = __expf(2.f*x);
  return 1.f - 2.f/(e+1.f);
}
__device__ __forceinline__ unsigned int cvtpk_bf16(float lo, float hi){
  unsigned int r;
  asm volatile("v_cvt_pk_bf16_f32 %0, %1, %2" : "=v"(r) : "v"(lo), "v"(hi));
  return r;
}
__device__ __forceinline__ void plane_swap(unsigned int &a, unsigned int &b){
  asm volatile("v_permlane32_swap_b32 %0, %1" : "+v"(a), "+v"(b));
}

// ---------------- input dtype detection (bf16 vs fp32 device buffers) ----------------
__global__ void detect_k(const void* xraw, int* flag){
  const bf16* p = (const bf16*)xraw;
  int good = 0;
  for (int i = threadIdx.x; i < 4096; i += 256){
    float v = fabsf(b2f(p[i]));
    if (v > 0.0009765625f && v < 16.f) good++;
  }
  __shared__ int s[256];
  s[threadIdx.x] = good;
  __syncthreads();
  for (int d = 128; d; d >>= 1){
    if (threadIdx.x < d) s[threadIdx.x] += s[threadIdx.x + d];
    __syncthreads();
  }
  if (threadIdx.x == 0) *flag = (s[0] < 3500) ? 1 : 0;
}

// ---------------- import (params to fp32 ws) ----------------
struct ImpEnt { const void* src; void* dst; int n; };
struct ImpArgs { ImpEnt e[23]; };
__global__ __launch_bounds__(256) void import_k(ImpArgs a, const int* __restrict__ flag){
  ImpEnt en = a.e[blockIdx.y];
  const bool f32 = (*flag != 0);
  for (int i = blockIdx.x*256 + threadIdx.x; i < en.n; i += gridDim.x*256){
    float v = f32 ? ((const float*)en.src)[i] : b2f(((const bf16*)en.src)[i]);
    ((float*)en.dst)[i] = v;
  }
}

// ---------------- weight repack to MFMA-B fragment layout ----------------
__global__ __launch_bounds__(256) void repack5_k(const float* __restrict__ W0,
    const float* __restrict__ W1p, const float* __restrict__ W2p,
    const float* __restrict__ W3p, const float* __restrict__ W4p,
    bf16* __restrict__ dst){
  int idx = blockIdx.x*256 + threadIdx.x;
  const float* Ws[5] = {W0, W1p, W2p, W3p, W4p};
  int o = idx >> 14;
  int rem = idx & 16383;
  int j = rem & 7, l = (rem >> 3) & 63, t = rem >> 9;
  int ks = t >> 3, cb = t & 7;
  int k = ks*32 + (l>>4)*8 + j;
  int c = cb*16 + (l&15);
  dst[idx] = f2b(Ws[o][k*128 + c]);
}

// mode 0: plain; mode 1: perm'd cols p(c)=(c&15)*8+(c>>4); mode 2: We 32x8 padded to 16 cols
struct RepEnt { const float* src; bf16* dst; int total; int ncb_log; int dout; int mode; };
__global__ __launch_bounds__(256) void repack_k(RepEnt e0, RepEnt e1, RepEnt e2,
                                                RepEnt e3, RepEnt e4){
  RepEnt en = (blockIdx.y == 0) ? e0 : (blockIdx.y == 1) ? e1 :
              (blockIdx.y == 2) ? e2 : (blockIdx.y == 3) ? e3 : e4;
  int idx = blockIdx.x*256 + threadIdx.x;
  if (idx >= en.total) return;
  int j = idx & 7, l = (idx >> 3) & 63, t = idx >> 9;
  if (en.mode == 2){
    int k = (l>>4)*8 + j;
    int c = l & 15;
    en.dst[idx] = (c < 8) ? f2b(en.src[k*8 + c]) : f2b(0.f);
    return;
  }
  int ncbm = (1 << en.ncb_log) - 1;
  int ks = t >> en.ncb_log, cb = t & ncbm;
  int k = ks*32 + (l>>4)*8 + j;
  int c = cb*16 + (l&15);
  if (en.mode == 1) c = ((c & 15) << 3) | (c >> 4);
  en.dst[idx] = f2b(en.src[k*en.dout + c]);
}

// ---------------- fused 5-way projection GEMM (reads raw x, dtype-flag branch) -------
__global__ __launch_bounds__(256) void gemm5_k(const void* __restrict__ xraw,
    const int* __restrict__ flag,
    const bf16* __restrict__ Wrep, const float* __restrict__ bias5,
    bf16* __restrict__ proj5){
  const int tid = threadIdx.x;
  const int wid = tid >> 6, l = tid & 63;
  const long r0 = (long)blockIdx.x*64 + wid*16;
  const bool f32 = (*flag != 0);
  short8 af[4];
  if (f32){
    const float* fr = (const float*)xraw + (r0 + (l&15))*128;
    #pragma unroll
    for (int ks=0; ks<4; ks++){
      float4 a = *(const float4*)(fr + ks*32 + (l>>4)*8);
      float4 b = *(const float4*)(fr + ks*32 + (l>>4)*8 + 4);
      union{ unsigned int u[4]; short8 s; } c;
      c.u[0]=cvtpk_bf16(a.x,a.y); c.u[1]=cvtpk_bf16(a.z,a.w);
      c.u[2]=cvtpk_bf16(b.x,b.y); c.u[3]=cvtpk_bf16(b.z,b.w);
      af[ks] = c.s;
    }
  } else {
    const short* Arow = (const short*)xraw + (r0 + (l&15))*128;
    #pragma unroll
    for (int ks=0; ks<4; ks++)
      af[ks] = *(const short8*)(Arow + ks*32 + (l>>4)*8);
  }
  const short8* Wp = (const short8*)Wrep;
  const int cc = l & 15, rr = (l >> 4) * 4;
  #pragma unroll 1
  for (int o=0; o<5; o++){
    f32x4 acc[8];
    #pragma unroll
    for (int cb=0; cb<8; cb++) acc[cb] = (f32x4){0.f,0.f,0.f,0.f};
    #pragma unroll
    for (int ks=0; ks<4; ks++){
      #pragma unroll
      for (int cb=0; cb<8; cb++){
        short8 bf = Wp[(o*32 + ks*8 + cb)*64 + l];
        acc[cb] = __builtin_amdgcn_mfma_f32_16x16x32_bf16(af[ks], bf, acc[cb], 0,0,0);
      }
    }
    bf16* outb = proj5 + (long)o*kN*128;
    #pragma unroll
    for (int cb=0; cb<8; cb++){
      float bb = bias5[o*128 + cb*16 + cc];
      #pragma unroll
      for (int r=0; r<4; r++){
        long row = r0 + rr + r;
        outb[row*128 + cb*16 + cc] = f2b(acc[cb][r] + bb);
      }
    }
  }
}

// ---------------- generic MFMA GEMM ----------------
template<int DIN, int DOUT, int EPI>
__global__ __launch_bounds__(256) void gemm_mfma_k(const bf16* __restrict__ A,
    const bf16* __restrict__ Wrep, const float* __restrict__ bias,
    bf16* __restrict__ C){
  constexpr int KS = DIN/32, NCB = DOUT/16;
  const int tid = threadIdx.x;
  const int wid = tid >> 6, l = tid & 63;
  const long r0 = (long)blockIdx.x*64 + wid*16;
  const short* Arow = (const short*)(A + (r0 + (l&15))*(long)DIN);
  short8 af[KS];
  #pragma unroll
  for (int ks=0; ks<KS; ks++)
    af[ks] = *(const short8*)(Arow + ks*32 + (l>>4)*8);
  f32x4 acc[NCB];
  #pragma unroll
  for (int cb=0; cb<NCB; cb++) acc[cb] = (f32x4){0.f,0.f,0.f,0.f};
  const short8* Wp = (const short8*)Wrep;
  #pragma unroll
  for (int ks=0; ks<KS; ks++){
    #pragma unroll
    for (int cb=0; cb<NCB; cb++){
      short8 bf = Wp[(ks*NCB + cb)*64 + l];
      acc[cb] = __builtin_amdgcn_mfma_f32_16x16x32_bf16(af[ks], bf, acc[cb], 0,0,0);
    }
  }
  const int cc = l & 15, rr = (l >> 4) * 4;
  #pragma unroll
  for (int cb=0; cb<NCB; cb++){
    float bb = bias[cb*16 + cc];
    #pragma unroll
    for (int r=0; r<4; r++){
      long row = r0 + rr + r;
      float v = acc[cb][r] + bb;
      if (EPI == 2) v = 0.5f*v*(1.f + erff(v*0.70710678118654752f));
      C[row*DOUT + cb*16 + cc] = f2b(v);
    }
  }
}

// ---------------- CSR build ----------------
__global__ void hist_k(const int* __restrict__ dstA, int* __restrict__ cnt){
  int e = blockIdx.x*256 + threadIdx.x;
  if (e < kE) atomicAdd(&cnt[dstA[e]], 1);
}

__global__ __launch_bounds__(1024) void scan_k(const int* __restrict__ cnt, int* __restrict__ rowptr){
  __shared__ int part[1024];
  const int t = threadIdx.x;
  const int base = t*32;
  int s = 0;
  #pragma unroll
  for (int i=0;i<32;i++) s += cnt[base+i];
  part[t] = s;
  __syncthreads();
  for (int d=1; d<1024; d<<=1){
    int v = (t>=d) ? part[t-d] : 0;
    __syncthreads();
    part[t] += v;
    __syncthreads();
  }
  int run = (t==0) ? 0 : part[t-1];
  for (int i=0;i<32;i++){ rowptr[base+i] = run; run += cnt[base+i]; }
  if (t == 1023) rowptr[kN] = run;
}

__global__ void scatter_k(const int* __restrict__ dstA, const int* __restrict__ rowptr,
                          int* __restrict__ cursor, int* __restrict__ eidx){
  int e = blockIdx.x*256 + threadIdx.x;
  if (e < kE){
    int d = dstA[e];
    int p = atomicAdd(&cursor[d], 1);
    eidx[rowptr[d]+p] = e;
  }
}

// ---------------- edge3 v4: CSR-ordered, MFMA edge GEMM (perm'd cols) + MFMA eb,
// direct coalesced epilogue gather (no LDS stage), graph-locality XCD swizzle.
__global__ __launch_bounds__(256) void edge3_k(const void* __restrict__ ea_raw,
    const int* __restrict__ flag,
    const int* __restrict__ eidx, const int* __restrict__ srcA,
    const int* __restrict__ dstA,
    const bf16* __restrict__ xs, const bf16* __restrict__ xd,
    const bf16* __restrict__ WeR_edge,     // perm'd: out col c -> orig ch (c&15)*8+(c>>4)
    const bf16* __restrict__ WeR_eb,       // We 32x8 padded to 16 cols, frag layout
    const float* __restrict__ att_f, const float* __restrict__ be_f,
    float* __restrict__ expal_t, float* __restrict__ ebuf_t,
    unsigned short* __restrict__ epack, int* __restrict__ src_t){
  __shared__ int sEid[64], sSrc[64], sDst[64];
  __shared__ float sAlphaF[64*4];
  const int tid = threadIdx.x;
  const int w = tid >> 6, l = tid & 63;
  const int p = blockIdx.x;
  const int bid = (p & 7) * (gridDim.x >> 3) + (p >> 3);
  const long t0 = (long)bid * 64;
  const bool f32 = (*flag != 0);

  if (tid < 64){
    int e = eidx[t0 + tid];
    int s = srcA[e], d = dstA[e];
    sEid[tid] = e; sSrc[tid] = s; sDst[tid] = d;
    src_t[t0 + tid] = s;
    epack[t0 + tid] = (unsigned short)(((s & 255) << 8) | (d & 255));
  }
  __syncthreads();

  short8 af;
  {
    long eoff = (long)sEid[w*16 + (l&15)]*32 + (l>>4)*8;
    if (f32){
      const float* er = (const float*)ea_raw + eoff;
      float4 a = *(const float4*)er;
      float4 b = *(const float4*)(er + 4);
      union{ unsigned int u[4]; short8 s; } c;
      c.u[0]=cvtpk_bf16(a.x,a.y); c.u[1]=cvtpk_bf16(a.z,a.w);
      c.u[2]=cvtpk_bf16(b.x,b.y); c.u[3]=cvtpk_bf16(b.z,b.w);
      af = c.s;
    } else {
      af = *(const short8*)((const short*)ea_raw + eoff);
    }
  }

  f32x4 acc[8], acc_eb;
  #pragma unroll
  for (int cb=0; cb<8; cb++){
    short8 wb = *(const short8*)((const short*)WeR_edge + (cb*64 + l)*8);
    acc[cb] = __builtin_amdgcn_mfma_f32_16x16x32_bf16(af, wb,
                (f32x4){0.f,0.f,0.f,0.f}, 0,0,0);
  }
  {
    short8 wbe = *(const short8*)((const short*)WeR_eb + l*8);
    acc_eb = __builtin_amdgcn_mfma_f32_16x16x32_bf16(af, wbe,
                (f32x4){0.f,0.f,0.f,0.f}, 0,0,0);
  }

  const int c15 = l & 15;
  const float be_v = be_f[c15 & 7];
  float4 at0 = *(const float4*)(att_f + c15*8);
  float4 at1 = *(const float4*)(att_f + c15*8 + 4);
  const float attv[8] = {at0.x,at0.y,at0.z,at0.w, at1.x,at1.y,at1.z,at1.w};
  union U8 { short8 s8; unsigned short u[8]; };
  U8 gx[4], gd[4];
  #pragma unroll
  for (int r=0; r<4; r++){
    int e_l = w*16 + (l>>4)*4 + r;
    gx[r].s8 = *(const short8*)((const short*)xs + (long)sSrc[e_l]*128 + c15*8);
    gd[r].s8 = *(const short8*)((const short*)xd + (long)sDst[e_l]*128 + c15*8);
  }
  #pragma unroll
  for (int r=0; r<4; r++){
    int e_l = w*16 + (l>>4)*4 + r;
    float hsum = 0.f;
    #pragma unroll
    for (int cb=0; cb<8; cb++){
      float v = acc[cb][r] + b2f_raw(gx[r].u[cb]) + b2f_raw(gd[r].u[cb]);
      hsum += tanh_fast(v) * attv[cb];
    }
    hsum += __shfl_xor(hsum,1);
    hsum += __shfl_xor(hsum,2);
    if ((c15 & 3) == 0) sAlphaF[e_l*4 + (c15>>2)] = __expf(hsum);
    if (c15 < 8) ebuf_t[(long)c15*kE + t0 + e_l] = acc_eb[r] + be_v;
  }
  __syncthreads();
  if (tid < 64)
    *(float4*)&expal_t[(t0 + tid)*4] = *(float4*)&sAlphaF[tid*4];
}

// ---------------- GAT aggregate: 32 lanes/node, single pass, graph-locality swizzle --
__global__ __launch_bounds__(256) void gat_agg_k(const float* __restrict__ expal,
    const int* __restrict__ rowptr, const int* __restrict__ src_t,
    const bf16* __restrict__ xs, const float* __restrict__ gatb_f,
    bf16* __restrict__ h_local){
  const int tid = threadIdx.x;
  const int grp = tid >> 5;
  const int l   = tid & 31;
  const int p   = blockIdx.x;
  const int bid = (p & 7) * (gridDim.x >> 3) + (p >> 3);
  const int v   = bid*8 + grp;
  const int c0  = l*4;
  const int head = l >> 3;
  const int beg = rowptr[v], end = rowptr[v+1];
  float den = 0.f, o0 = 0.f, o1 = 0.f, o2 = 0.f, o3 = 0.f;
  const unsigned short* xsu = (const unsigned short*)xs;
  for (int t = beg; t < end; t++){
    float w = expal[(long)t*4 + head];
    long s = src_t[t];
    ushort4 a = *(const ushort4*)(xsu + s*128 + c0);
    den += w;
    o0 += w*b2f_raw(a.x); o1 += w*b2f_raw(a.y);
    o2 += w*b2f_raw(a.z); o3 += w*b2f_raw(a.w);
  }
  float inv = 1.f/(den + 1e-16f);
  float4 gb = *(const float4*)(gatb_f + c0);
  unsigned int lo = cvtpk_bf16(o0*inv + gb.x, o1*inv + gb.y);
  unsigned int hi = cvtpk_bf16(o2*inv + gb.z, o3*inv + gb.w);
  *(uint2*)&((unsigned short*)h_local)[(long)v*128 + c0] = (uint2){lo, hi};
}

// ---------------- MFMA flash attention (no-max softmax): block=(g,h), 8 waves -------
// Scores + bias bounded (~±13) -> exp safe in fp32 without max subtraction.
// LDS bias scatter per key-tile (read-then-zero); K-frag prefetch depth 2.
__global__ __launch_bounds__(512, 6) void attn2_k(const bf16* __restrict__ qb,
    const bf16* __restrict__ kb, const bf16* __restrict__ vb,
    const float* __restrict__ ebuf_t, const unsigned short* __restrict__ epack,
    const int* __restrict__ rowptr, bf16* __restrict__ hattn){
  __shared__ short Vf[16*64*8];     // 16 KB
  __shared__ float sb[256*33];      // 33.8 KB
  const int bid = blockIdx.x;
  const int h = (bid >> 3) >> 4;
  const int g = (((bid >> 3) & 15) << 3) | (bid & 7);
  const int tid = threadIdx.x;
  const int w = tid >> 6, l = tid & 63;
  const int q31 = l & 31, hi = l >> 5;
  const int nbase = g << 8;

  for (int s2 = tid; s2 < 1024; s2 += 512){
    int f = s2 >> 6, ll = s2 & 63;
    int keyb = (f>>1)*32 + (f&1)*16 + ((ll>>5)*8);
    int d = ll & 15;
    short tmp[8];
    #pragma unroll
    for (int j=0;j<8;j++)
      tmp[j] = ((const short*)vb)[((long)(nbase + keyb + j))*128 + h*16 + d];
    *(short8*)&Vf[s2*8] = *(short8*)tmp;
  }
  for (int i = tid; i < 256*33; i += 512) sb[i] = 0.f;
  short8 qf = *(const short8*)((const short*)qb + ((long)(nbase + w*32 + q31))*128 + h*16 + hi*8);
  __syncthreads();

  float lsum = 0.f;
  f32x16 oacc = {0.f,0.f,0.f,0.f,0.f,0.f,0.f,0.f,0.f,0.f,0.f,0.f,0.f,0.f,0.f,0.f};
  short8 kf = *(const short8*)((const short*)kb + ((long)(nbase + q31))*128 + h*16 + hi*8);
  #pragma unroll 1
  for (int kt = 0; kt < 8; kt++){
    int rb = rowptr[nbase + kt*32];
    int re = rowptr[nbase + kt*32 + 32];
    for (int t = rb + tid; t < re; t += 512){
      unsigned int p = epack[t];
      atomicAdd(&sb[(p>>8)*33 + (p&31)], ebuf_t[(long)h*kE + t]);
    }
    __syncthreads();
    short8 kcur = kf;
    if (kt < 7)
      kf = *(const short8*)((const short*)kb +
            ((long)(nbase + (kt+1)*32 + q31))*128 + h*16 + hi*8);
    f32x16 acc = {0.f,0.f,0.f,0.f,0.f,0.f,0.f,0.f,0.f,0.f,0.f,0.f,0.f,0.f,0.f,0.f};
    acc = __builtin_amdgcn_mfma_f32_32x32x16_bf16(kcur, qf, acc, 0, 0, 0);
    float s[16];
    float* brow = &sb[(w*32 + q31)*33];
    #pragma unroll
    for (int r=0;r<16;r++){
      int krow = (r&3) + 8*(r>>2) + 4*hi;
      s[r] = fmaf(acc[r], 0.25f, brow[krow]);
      brow[krow] = 0.f;
    }
    __syncthreads();
    float psum = 0.f;
    #pragma unroll
    for (int r=0;r<16;r++){ s[r] = __expf(s[r]); psum += s[r]; }
    lsum += psum;
    unsigned int a  = cvtpk_bf16(s[0],  s[1]);
    unsigned int b  = cvtpk_bf16(s[2],  s[3]);
    unsigned int c  = cvtpk_bf16(s[4],  s[5]);
    unsigned int d  = cvtpk_bf16(s[6],  s[7]);
    unsigned int e  = cvtpk_bf16(s[8],  s[9]);
    unsigned int f  = cvtpk_bf16(s[10], s[11]);
    unsigned int g2 = cvtpk_bf16(s[12], s[13]);
    unsigned int h2 = cvtpk_bf16(s[14], s[15]);
    plane_swap(a, c); plane_swap(b, d); plane_swap(e, g2); plane_swap(f, h2);
    union { unsigned int u[4]; short8 s8; } A1, A2;
    A1.u[0]=a; A1.u[1]=b; A1.u[2]=c; A1.u[3]=d;
    A2.u[0]=e; A2.u[1]=f; A2.u[2]=g2; A2.u[3]=h2;
    short8 v1 = *(short8*)&Vf[((kt*2+0)*64 + l)*8];
    short8 v2 = *(short8*)&Vf[((kt*2+1)*64 + l)*8];
    oacc = __builtin_amdgcn_mfma_f32_32x32x16_bf16(A1.s8, v1, oacc, 0,0,0);
    oacc = __builtin_amdgcn_mfma_f32_32x32x16_bf16(A2.s8, v2, oacc, 0,0,0);
  }
  lsum += __shfl_xor(lsum, 32);
  float linv = 1.f / lsum;
  #pragma unroll
  for (int r=0;r<16;r++){
    int qrow = (r&3) + 8*(r>>2) + 4*hi;
    float li = __shfl(linv, qrow);
    float ov = oacc[r]*li;
    if (q31 < 16)
      hattn[((long)(nbase + w*32 + qrow))*128 + h*16 + q31] = f2b(ov);
  }
}

// ---------------- residual add + LayerNorm ----------------
__global__ __launch_bounds__(256) void combine_ln_k(const void* __restrict__ a,
    const bf16* __restrict__ b, const bf16* __restrict__ c3,
    const float* __restrict__ g, const float* __restrict__ bb,
    void* __restrict__ outp, const int* __restrict__ flag,
    int a_raw, int is_final){
  const int tid = threadIdx.x;
  const int lane = tid & 63;
  const long row = (long)blockIdx.x*4 + (tid>>6);
  const long base = row*128;
  float a0, a1;
  if (a_raw && (*flag)){
    const float* ap = (const float*)a;
    a0 = ap[base+lane]; a1 = ap[base+lane+64];
  } else {
    const bf16* ap = (const bf16*)a;
    a0 = b2f(ap[base+lane]); a1 = b2f(ap[base+lane+64]);
  }
  float v0 = a0 + b2f(b[base+lane]);
  float v1 = a1 + b2f(b[base+lane+64]);
  if (c3){ v0 += b2f(c3[base+lane]); v1 += b2f(c3[base+lane+64]); }
  float s = v0 + v1;
  #pragma unroll
  for (int o=1; o<64; o<<=1) s += __shfl_xor(s, o);
  float mean = s * (1.f/128.f);
  float d0 = v0 - mean, d1 = v1 - mean;
  float q = d0*d0 + d1*d1;
  #pragma unroll
  for (int o=1; o<64; o<<=1) q += __shfl_xor(q, o);
  float r = rsqrtf(q*(1.f/128.f) + 1e-5f);
  float r0v = d0*r*g[lane]    + bb[lane];
  float r1v = d1*r*g[lane+64] + bb[lane+64];
  if (is_final && (*flag)){
    float* o = (float*)outp;
    o[base+lane]    = r0v;
    o[base+lane+64] = r1v;
  } else {
    bf16* o = (bf16*)outp;
    o[base+lane]    = f2b(r0v);
    o[base+lane+64] = f2b(r1v);
  }
}

// =====================================================================================
extern "C" void kernel_launch(void* const* d_in, const int* in_sizes, int n_in,
                              void* d_out, int out_size, void* d_ws, size_t ws_size,
                              hipStream_t stream){
  const void* x_raw   = d_in[0];
  const void* ea_raw  = d_in[1];
  const int*  ei      = (const int*)d_in[25];
  const int* srcA = ei;
  const int* dstA = ei + kE;

  char* ws = (char*)d_ws;
  size_t off = 0;
  auto alloc = [&](size_t bytes)->void*{
    void* p = ws + off;
    off = (off + bytes + 255) & ~(size_t)255;
    return p;
  };
  int*   flag    = (int*)alloc(4);
  float* Wsrc_f  = (float*)alloc(16384*4);
  float* Wdst_f  = (float*)alloc(16384*4);
  float* Wedge_f = (float*)alloc(4096*4);
  float* att_f   = (float*)alloc(128*4);
  float* gatb_f  = (float*)alloc(128*4);
  float* Wq_f    = (float*)alloc(16384*4);
  float* Wk_f    = (float*)alloc(16384*4);
  float* Wv_f    = (float*)alloc(16384*4);
  float* Wo_f    = (float*)alloc(16384*4);
  float* bo_f    = (float*)alloc(128*4);
  float* We_f    = (float*)alloc(256*4);
  float* be_f    = (float*)alloc(8*4);
  float* ln1g_f  = (float*)alloc(128*4);
  float* ln1b_f  = (float*)alloc(128*4);
  float* W1_f    = (float*)alloc(32768*4);
  float* b1_f    = (float*)alloc(256*4);
  float* W2_f    = (float*)alloc(32768*4);
  float* b2_f    = (float*)alloc(128*4);
  float* ln2g_f  = (float*)alloc(128*4);
  float* ln2b_f  = (float*)alloc(128*4);
  float* bias5   = (float*)alloc(640*4);
  bf16*  Wrep5   = (bf16*)alloc((size_t)5*16384*2);
  bf16*  WoR     = (bf16*)alloc((size_t)16384*2);
  bf16*  W1R     = (bf16*)alloc((size_t)32768*2);
  bf16*  W2R     = (bf16*)alloc((size_t)32768*2);
  bf16*  WeR     = (bf16*)alloc((size_t)4096*2);
  bf16*  WeRb    = (bf16*)alloc((size_t)512*2);
  bf16*  proj5   = (bf16*)alloc((size_t)5*kN*128*2);
  bf16* xs   = proj5;
  bf16* xd   = proj5 + (size_t)kN*128;
  bf16* qb   = proj5 + (size_t)2*kN*128;
  bf16* kbuf = proj5 + (size_t)3*kN*128;
  bf16* vbuf = proj5 + (size_t)4*kN*128;
  int* cnt        = (int*)alloc((size_t)2*kN*4);
  int* cursor     = cnt + kN;
  int* rowptr     = (int*)alloc((size_t)(kN+1)*4);
  int* eidx       = (int*)alloc((size_t)kE*4);
  unsigned short* epack = (unsigned short*)alloc((size_t)kE*2);
  float* ebuf_t   = (float*)alloc((size_t)8*kE*4);
  float* expal_t  = (float*)alloc((size_t)kE*4*4);
  int*   src_t    = (int*)alloc((size_t)kE*4);
  bf16* h_local   = (bf16*)alloc((size_t)kN*128*2);
  bf16* hattn_pre = (bf16*)alloc((size_t)kN*128*2);
  bf16* h_attn    = (bf16*)alloc((size_t)kN*128*2);
  bf16* hbuf      = (bf16*)alloc((size_t)kN*128*2);
  bf16* tbuf      = (bf16*)alloc((size_t)kN*256*2);
  bf16* f2buf     = (bf16*)alloc((size_t)kN*128*2);
  (void)ws_size; (void)in_sizes; (void)n_in; (void)out_size;

  dim3 b256(256);

  detect_k<<<1, b256, 0, stream>>>(x_raw, flag);
  hipMemsetAsync(bias5, 0, 256*4, stream);
  hipMemsetAsync(cnt, 0, (size_t)2*kN*4, stream);

  // CSR by dst (edge3/gat order + attn bias scatter)
  hist_k<<<kE/256, b256, 0, stream>>>(dstA, cnt);
  scan_k<<<1, 1024, 0, stream>>>(cnt, rowptr);
  scatter_k<<<kE/256, b256, 0, stream>>>(dstA, rowptr, cursor, eidx);

  ImpArgs ia;
  const void* srcs[23] = {d_in[2], d_in[3], d_in[4], d_in[5], d_in[6],
                          d_in[7], d_in[8], d_in[9], d_in[10], d_in[11], d_in[12],
                          d_in[13], d_in[14], d_in[15], d_in[16], d_in[17], d_in[18],
                          d_in[19], d_in[20], d_in[21], d_in[22], d_in[23], d_in[24]};
  void* dsts[23] = {Wsrc_f, Wdst_f, Wedge_f, att_f, gatb_f,
                    Wq_f, bias5+256, Wk_f, bias5+384, Wv_f, bias5+512,
                    Wo_f, bo_f, We_f, be_f, ln1g_f, ln1b_f,
                    W1_f, b1_f, W2_f, b2_f, ln2g_f, ln2b_f};
  int ns[23] = {16384, 16384, 4096, 128, 128,
                16384, 128, 16384, 128, 16384, 128,
                16384, 128, 256, 8, 128, 128,
                32768, 256, 32768, 128, 128, 128};
  for (int i=0;i<23;i++){ ia.e[i].src=srcs[i]; ia.e[i].dst=dsts[i]; ia.e[i].n=ns[i]; }
  import_k<<<dim3(64,23), b256, 0, stream>>>(ia, flag);

  repack5_k<<<(5*16384)/256, b256, 0, stream>>>(Wsrc_f, Wdst_f, Wq_f, Wk_f, Wv_f, Wrep5);
  RepEnt ro{Wo_f, WoR, 16384, 3, 128, 0};
  RepEnt r1{W1_f, W1R, 32768, 4, 256, 0};
  RepEnt r2{W2_f, W2R, 32768, 3, 128, 0};
  RepEnt re{Wedge_f, WeR, 4096, 3, 128, 1};
  RepEnt rb{We_f, WeRb, 512, 0, 8, 2};
  repack_k<<<dim3(128,5), b256, 0, stream>>>(ro, r1, r2, re, rb);

  gemm5_k<<<kN/64, b256, 0, stream>>>(x_raw, flag, Wrep5, bias5, proj5);

  edge3_k<<<kE/64, b256, 0, stream>>>(ea_raw, flag, eidx, srcA, dstA, xs, xd,
                                      WeR, WeRb, att_f, be_f,
                                      expal_t, ebuf_t, epack, src_t);

  gat_agg_k<<<kN/8, b256, 0, stream>>>(expal_t, rowptr, src_t, xs, gatb_f, h_local);

  attn2_k<<<kG*kHA, dim3(512), 0, stream>>>(qb, kbuf, vbuf, ebuf_t, epack, rowptr, hattn_pre);
  gemm_mfma_k<128,128,1><<<kN/64, b256, 0, stream>>>(hattn_pre, WoR, bo_f, h_attn);

  combine_ln_k<<<kN/4, b256, 0, stream>>>(x_raw, h_local, h_attn, ln1g_f, ln1b_f,
                                          hbuf, flag, 1, 0);

  gemm_mfma_k<128,256,2><<<kN/64, b256, 0, stream>>>(hbuf, W1R, b1_f, tbuf);
  gemm_mfma_k<256,128,1><<<kN/64, b256, 0, stream>>>(tbuf, W2R, b2_f, f2buf);

  combine_ln_k<<<kN/4, b256, 0, stream>>>(hbuf, f2buf, nullptr, ln2g_f, ln2b_f,
                                          d_out, flag, 0, 1);
}

// Round 13
// 225.553 us; speedup vs baseline: 1.5071x; 1.0217x over previous
//
#include <hip/hip_runtime.h>
#include <hip/hip_bf16.h>

typedef __hip_bfloat16 bf16;
typedef __hip_bfloat162 bf162;
typedef __attribute__((ext_vector_type(8))) short short8;
typedef __attribute__((ext_vector_type(4))) float f32x4;
typedef __attribute__((ext_vector_type(16))) float f32x16;

constexpr int kN   = 32768;   // nodes
constexpr int kG   = 128;     // graphs
constexpr int kE   = 262144;  // edges
constexpr int kHA  = 8;       // global attn heads

__device__ __forceinline__ float b2f(bf16 v){ return __bfloat162float(v); }
__device__ __forceinline__ bf16  f2b(float v){ return __float2bfloat16(v); }
__device__ __forceinline__ float b2f_raw(unsigned short u){
  return __uint_as_float((unsigned)u << 16);
}
__device__ __forceinline__ float tanh_fast(float x){
  float e = __expf(2.f*x);
  return 1.f - 2.f/(e+1.f);
}
__device__ __forceinline__ unsigned int cvtpk_bf16(float lo, float hi){
  unsigned int r;
  asm volatile("v_cvt_pk_bf16_f32 %0, %1, %2" : "=v"(r) : "v"(lo), "v"(hi));
  return r;
}
__device__ __forceinline__ void plane_swap(unsigned int &a, unsigned int &b){
  asm volatile("v_permlane32_swap_b32 %0, %1" : "+v"(a), "+v"(b));
}

// ---------------- input dtype detection (bf16 vs fp32 device buffers) ----------------
__global__ void detect_k(const void* xraw, int* flag){
  const bf16* p = (const bf16*)xraw;
  int good = 0;
  for (int i = threadIdx.x; i < 4096; i += 256){
    float v = fabsf(b2f(p[i]));
    if (v > 0.0009765625f && v < 16.f) good++;
  }
  __shared__ int s[256];
  s[threadIdx.x] = good;
  __syncthreads();
  for (int d = 128; d; d >>= 1){
    if (threadIdx.x < d) s[threadIdx.x] += s[threadIdx.x + d];
    __syncthreads();
  }
  if (threadIdx.x == 0) *flag = (s[0] < 3500) ? 1 : 0;
}

// ---------------- import (params to fp32 ws) ----------------
struct ImpEnt { const void* src; void* dst; int n; };
struct ImpArgs { ImpEnt e[23]; };
__global__ __launch_bounds__(256) void import_k(ImpArgs a, const int* __restrict__ flag){
  ImpEnt en = a.e[blockIdx.y];
  const bool f32 = (*flag != 0);
  for (int i = blockIdx.x*256 + threadIdx.x; i < en.n; i += gridDim.x*256){
    float v = f32 ? ((const float*)en.src)[i] : b2f(((const bf16*)en.src)[i]);
    ((float*)en.dst)[i] = v;
  }
}

// ---------------- weight repack to MFMA-B fragment layout ----------------
__global__ __launch_bounds__(256) void repack5_k(const float* __restrict__ W0,
    const float* __restrict__ W1p, const float* __restrict__ W2p,
    const float* __restrict__ W3p, const float* __restrict__ W4p,
    bf16* __restrict__ dst){
  int idx = blockIdx.x*256 + threadIdx.x;
  const float* Ws[5] = {W0, W1p, W2p, W3p, W4p};
  int o = idx >> 14;
  int rem = idx & 16383;
  int j = rem & 7, l = (rem >> 3) & 63, t = rem >> 9;
  int ks = t >> 3, cb = t & 7;
  int k = ks*32 + (l>>4)*8 + j;
  int c = cb*16 + (l&15);
  dst[idx] = f2b(Ws[o][k*128 + c]);
}

// mode 0: plain; mode 1: perm'd cols p(c)=(c&15)*8+(c>>4); mode 2: We 32x8 padded to 16 cols
struct RepEnt { const float* src; bf16* dst; int total; int ncb_log; int dout; int mode; };
__global__ __launch_bounds__(256) void repack_k(RepEnt e0, RepEnt e1, RepEnt e2,
                                                RepEnt e3, RepEnt e4){
  RepEnt en = (blockIdx.y == 0) ? e0 : (blockIdx.y == 1) ? e1 :
              (blockIdx.y == 2) ? e2 : (blockIdx.y == 3) ? e3 : e4;
  int idx = blockIdx.x*256 + threadIdx.x;
  if (idx >= en.total) return;
  int j = idx & 7, l = (idx >> 3) & 63, t = idx >> 9;
  if (en.mode == 2){
    int k = (l>>4)*8 + j;
    int c = l & 15;
    en.dst[idx] = (c < 8) ? f2b(en.src[k*8 + c]) : f2b(0.f);
    return;
  }
  int ncbm = (1 << en.ncb_log) - 1;
  int ks = t >> en.ncb_log, cb = t & ncbm;
  int k = ks*32 + (l>>4)*8 + j;
  int c = cb*16 + (l&15);
  if (en.mode == 1) c = ((c & 15) << 3) | (c >> 4);
  en.dst[idx] = f2b(en.src[k*en.dout + c]);
}

// ---------------- fused 5-way projection GEMM (reads raw x, dtype-flag branch) -------
__global__ __launch_bounds__(256) void gemm5_k(const void* __restrict__ xraw,
    const int* __restrict__ flag,
    const bf16* __restrict__ Wrep, const float* __restrict__ bias5,
    bf16* __restrict__ proj5){
  const int tid = threadIdx.x;
  const int wid = tid >> 6, l = tid & 63;
  const long r0 = (long)blockIdx.x*64 + wid*16;
  const bool f32 = (*flag != 0);
  short8 af[4];
  if (f32){
    const float* fr = (const float*)xraw + (r0 + (l&15))*128;
    #pragma unroll
    for (int ks=0; ks<4; ks++){
      float4 a = *(const float4*)(fr + ks*32 + (l>>4)*8);
      float4 b = *(const float4*)(fr + ks*32 + (l>>4)*8 + 4);
      union{ unsigned int u[4]; short8 s; } c;
      c.u[0]=cvtpk_bf16(a.x,a.y); c.u[1]=cvtpk_bf16(a.z,a.w);
      c.u[2]=cvtpk_bf16(b.x,b.y); c.u[3]=cvtpk_bf16(b.z,b.w);
      af[ks] = c.s;
    }
  } else {
    const short* Arow = (const short*)xraw + (r0 + (l&15))*128;
    #pragma unroll
    for (int ks=0; ks<4; ks++)
      af[ks] = *(const short8*)(Arow + ks*32 + (l>>4)*8);
  }
  const short8* Wp = (const short8*)Wrep;
  const int cc = l & 15, rr = (l >> 4) * 4;
  #pragma unroll 1
  for (int o=0; o<5; o++){
    f32x4 acc[8];
    #pragma unroll
    for (int cb=0; cb<8; cb++) acc[cb] = (f32x4){0.f,0.f,0.f,0.f};
    #pragma unroll
    for (int ks=0; ks<4; ks++){
      #pragma unroll
      for (int cb=0; cb<8; cb++){
        short8 bf = Wp[(o*32 + ks*8 + cb)*64 + l];
        acc[cb] = __builtin_amdgcn_mfma_f32_16x16x32_bf16(af[ks], bf, acc[cb], 0,0,0);
      }
    }
    bf16* outb = proj5 + (long)o*kN*128;
    #pragma unroll
    for (int cb=0; cb<8; cb++){
      float bb = bias5[o*128 + cb*16 + cc];
      #pragma unroll
      for (int r=0; r<4; r++){
        long row = r0 + rr + r;
        outb[row*128 + cb*16 + cc] = f2b(acc[cb][r] + bb);
      }
    }
  }
}

// ---------------- generic MFMA GEMM ----------------
template<int DIN, int DOUT, int EPI>
__global__ __launch_bounds__(256) void gemm_mfma_k(const bf16* __restrict__ A,
    const bf16* __restrict__ Wrep, const float* __restrict__ bias,
    bf16* __restrict__ C){
  constexpr int KS = DIN/32, NCB = DOUT/16;
  const int tid = threadIdx.x;
  const int wid = tid >> 6, l = tid & 63;
  const long r0 = (long)blockIdx.x*64 + wid*16;
  const short* Arow = (const short*)(A + (r0 + (l&15))*(long)DIN);
  short8 af[KS];
  #pragma unroll
  for (int ks=0; ks<KS; ks++)
    af[ks] = *(const short8*)(Arow + ks*32 + (l>>4)*8);
  f32x4 acc[NCB];
  #pragma unroll
  for (int cb=0; cb<NCB; cb++) acc[cb] = (f32x4){0.f,0.f,0.f,0.f};
  const short8* Wp = (const short8*)Wrep;
  #pragma unroll
  for (int ks=0; ks<KS; ks++){
    #pragma unroll
    for (int cb=0; cb<NCB; cb++){
      short8 bf = Wp[(ks*NCB + cb)*64 + l];
      acc[cb] = __builtin_amdgcn_mfma_f32_16x16x32_bf16(af[ks], bf, acc[cb], 0,0,0);
    }
  }
  const int cc = l & 15, rr = (l >> 4) * 4;
  #pragma unroll
  for (int cb=0; cb<NCB; cb++){
    float bb = bias[cb*16 + cc];
    #pragma unroll
    for (int r=0; r<4; r++){
      long row = r0 + rr + r;
      float v = acc[cb][r] + bb;
      if (EPI == 2) v = 0.5f*v*(1.f + erff(v*0.70710678118654752f));
      C[row*DOUT + cb*16 + cc] = f2b(v);
    }
  }
}

// ---------------- fused MFMA GEMM + residual add + LayerNorm ----------------
// out = LN( res2(optional raw) + res1 + (A@W + bias) ); DOUT=128.
// Row-LN via 4-step shfl_xor over the 16 cc-lanes owning each row.
template<int DIN, int FINAL>
__global__ __launch_bounds__(256) void gemm_ln_k(const bf16* __restrict__ A,
    const bf16* __restrict__ Wrep, const float* __restrict__ bias,
    const bf16* __restrict__ res1, const void* __restrict__ res2raw,
    const float* __restrict__ g, const float* __restrict__ bb,
    void* __restrict__ outp, const int* __restrict__ flag){
  constexpr int KS = DIN/32;
  const int tid = threadIdx.x;
  const int wid = tid >> 6, l = tid & 63;
  const long r0 = (long)blockIdx.x*64 + wid*16;
  const short* Arow = (const short*)(A + (r0 + (l&15))*(long)DIN);
  short8 af[KS];
  #pragma unroll
  for (int ks=0; ks<KS; ks++)
    af[ks] = *(const short8*)(Arow + ks*32 + (l>>4)*8);
  f32x4 acc[8];
  #pragma unroll
  for (int cb=0; cb<8; cb++) acc[cb] = (f32x4){0.f,0.f,0.f,0.f};
  const short8* Wp = (const short8*)Wrep;
  #pragma unroll
  for (int ks=0; ks<KS; ks++){
    #pragma unroll
    for (int cb=0; cb<8; cb++){
      short8 bf = Wp[(ks*8 + cb)*64 + l];
      acc[cb] = __builtin_amdgcn_mfma_f32_16x16x32_bf16(af[ks], bf, acc[cb], 0,0,0);
    }
  }
  const int cc = l & 15, rr = (l >> 4) * 4;
  const bool f32 = (*flag != 0);
  float v[8][4];
  #pragma unroll
  for (int cb=0; cb<8; cb++){
    float bv = bias[cb*16 + cc];
    #pragma unroll
    for (int r=0; r<4; r++){
      long row = r0 + rr + r;
      float t = acc[cb][r] + bv + b2f(res1[row*128 + cb*16 + cc]);
      if (res2raw){
        t += f32 ? ((const float*)res2raw)[row*128 + cb*16 + cc]
                 : b2f(((const bf16*)res2raw)[row*128 + cb*16 + cc]);
      }
      v[cb][r] = t;
    }
  }
  float gv[8], bbv[8];
  #pragma unroll
  for (int cb=0; cb<8; cb++){ gv[cb] = g[cb*16+cc]; bbv[cb] = bb[cb*16+cc]; }
  #pragma unroll
  for (int r=0; r<4; r++){
    float s = 0.f;
    #pragma unroll
    for (int cb=0; cb<8; cb++) s += v[cb][r];
    s += __shfl_xor(s,1); s += __shfl_xor(s,2);
    s += __shfl_xor(s,4); s += __shfl_xor(s,8);
    float mean = s * (1.f/128.f);
    float q = 0.f;
    #pragma unroll
    for (int cb=0; cb<8; cb++){ float d = v[cb][r]-mean; q += d*d; }
    q += __shfl_xor(q,1); q += __shfl_xor(q,2);
    q += __shfl_xor(q,4); q += __shfl_xor(q,8);
    float rstd = rsqrtf(q*(1.f/128.f) + 1e-5f);
    long row = r0 + rr + r;
    if (FINAL && f32){
      float* o = (float*)outp;
      #pragma unroll
      for (int cb=0; cb<8; cb++)
        o[row*128 + cb*16 + cc] = (v[cb][r]-mean)*rstd*gv[cb] + bbv[cb];
    } else {
      bf16* o = (bf16*)outp;
      #pragma unroll
      for (int cb=0; cb<8; cb++)
        o[row*128 + cb*16 + cc] = f2b((v[cb][r]-mean)*rstd*gv[cb] + bbv[cb]);
    }
  }
}

// ---------------- CSR build ----------------
__global__ void hist_k(const int* __restrict__ dstA, int* __restrict__ cnt){
  int e = blockIdx.x*256 + threadIdx.x;
  if (e < kE) atomicAdd(&cnt[dstA[e]], 1);
}

__global__ __launch_bounds__(1024) void scan_k(const int* __restrict__ cnt, int* __restrict__ rowptr){
  __shared__ int part[1024];
  const int t = threadIdx.x;
  const int base = t*32;
  int s = 0;
  #pragma unroll
  for (int i=0;i<32;i++) s += cnt[base+i];
  part[t] = s;
  __syncthreads();
  for (int d=1; d<1024; d<<=1){
    int v = (t>=d) ? part[t-d] : 0;
    __syncthreads();
    part[t] += v;
    __syncthreads();
  }
  int run = (t==0) ? 0 : part[t-1];
  for (int i=0;i<32;i++){ rowptr[base+i] = run; run += cnt[base+i]; }
  if (t == 1023) rowptr[kN] = run;
}

__global__ void scatter_k(const int* __restrict__ dstA, const int* __restrict__ rowptr,
                          int* __restrict__ cursor, int* __restrict__ eidx){
  int e = blockIdx.x*256 + threadIdx.x;
  if (e < kE){
    int d = dstA[e];
    int p = atomicAdd(&cursor[d], 1);
    eidx[rowptr[d]+p] = e;
  }
}

// ---------------- edge3 v4: CSR-ordered, MFMA edge GEMM (perm'd cols) + MFMA eb ------
__global__ __launch_bounds__(256) void edge3_k(const void* __restrict__ ea_raw,
    const int* __restrict__ flag,
    const int* __restrict__ eidx, const int* __restrict__ srcA,
    const int* __restrict__ dstA,
    const bf16* __restrict__ xs, const bf16* __restrict__ xd,
    const bf16* __restrict__ WeR_edge,
    const bf16* __restrict__ WeR_eb,
    const float* __restrict__ att_f, const float* __restrict__ be_f,
    float* __restrict__ expal_t, float* __restrict__ ebuf_t,
    unsigned short* __restrict__ epack, int* __restrict__ src_t){
  __shared__ int sEid[64], sSrc[64], sDst[64];
  __shared__ float sAlphaF[64*4];
  const int tid = threadIdx.x;
  const int w = tid >> 6, l = tid & 63;
  const int p = blockIdx.x;
  const int bid = (p & 7) * (gridDim.x >> 3) + (p >> 3);
  const long t0 = (long)bid * 64;
  const bool f32 = (*flag != 0);

  if (tid < 64){
    int e = eidx[t0 + tid];
    int s = srcA[e], d = dstA[e];
    sEid[tid] = e; sSrc[tid] = s; sDst[tid] = d;
    src_t[t0 + tid] = s;
    epack[t0 + tid] = (unsigned short)(((s & 255) << 8) | (d & 255));
  }
  __syncthreads();

  short8 af;
  {
    long eoff = (long)sEid[w*16 + (l&15)]*32 + (l>>4)*8;
    if (f32){
      const float* er = (const float*)ea_raw + eoff;
      float4 a = *(const float4*)er;
      float4 b = *(const float4*)(er + 4);
      union{ unsigned int u[4]; short8 s; } c;
      c.u[0]=cvtpk_bf16(a.x,a.y); c.u[1]=cvtpk_bf16(a.z,a.w);
      c.u[2]=cvtpk_bf16(b.x,b.y); c.u[3]=cvtpk_bf16(b.z,b.w);
      af = c.s;
    } else {
      af = *(const short8*)((const short*)ea_raw + eoff);
    }
  }

  f32x4 acc[8], acc_eb;
  #pragma unroll
  for (int cb=0; cb<8; cb++){
    short8 wb = *(const short8*)((const short*)WeR_edge + (cb*64 + l)*8);
    acc[cb] = __builtin_amdgcn_mfma_f32_16x16x32_bf16(af, wb,
                (f32x4){0.f,0.f,0.f,0.f}, 0,0,0);
  }
  {
    short8 wbe = *(const short8*)((const short*)WeR_eb + l*8);
    acc_eb = __builtin_amdgcn_mfma_f32_16x16x32_bf16(af, wbe,
                (f32x4){0.f,0.f,0.f,0.f}, 0,0,0);
  }

  const int c15 = l & 15;
  const float be_v = be_f[c15 & 7];
  float4 at0 = *(const float4*)(att_f + c15*8);
  float4 at1 = *(const float4*)(att_f + c15*8 + 4);
  const float attv[8] = {at0.x,at0.y,at0.z,at0.w, at1.x,at1.y,at1.z,at1.w};
  union U8 { short8 s8; unsigned short u[8]; };
  U8 gx[4], gd[4];
  #pragma unroll
  for (int r=0; r<4; r++){
    int e_l = w*16 + (l>>4)*4 + r;
    gx[r].s8 = *(const short8*)((const short*)xs + (long)sSrc[e_l]*128 + c15*8);
    gd[r].s8 = *(const short8*)((const short*)xd + (long)sDst[e_l]*128 + c15*8);
  }
  #pragma unroll
  for (int r=0; r<4; r++){
    int e_l = w*16 + (l>>4)*4 + r;
    float hsum = 0.f;
    #pragma unroll
    for (int cb=0; cb<8; cb++){
      float v = acc[cb][r] + b2f_raw(gx[r].u[cb]) + b2f_raw(gd[r].u[cb]);
      hsum += tanh_fast(v) * attv[cb];
    }
    hsum += __shfl_xor(hsum,1);
    hsum += __shfl_xor(hsum,2);
    if ((c15 & 3) == 0) sAlphaF[e_l*4 + (c15>>2)] = __expf(hsum);
    if (c15 < 8) ebuf_t[(long)c15*kE + t0 + e_l] = acc_eb[r] + be_v;
  }
  __syncthreads();
  if (tid < 64)
    *(float4*)&expal_t[(t0 + tid)*4] = *(float4*)&sAlphaF[tid*4];
}

// ---------------- GAT aggregate: 32 lanes/node, single pass, graph-locality swizzle --
__global__ __launch_bounds__(256) void gat_agg_k(const float* __restrict__ expal,
    const int* __restrict__ rowptr, const int* __restrict__ src_t,
    const bf16* __restrict__ xs, const float* __restrict__ gatb_f,
    bf16* __restrict__ h_local){
  const int tid = threadIdx.x;
  const int grp = tid >> 5;
  const int l   = tid & 31;
  const int p   = blockIdx.x;
  const int bid = (p & 7) * (gridDim.x >> 3) + (p >> 3);
  const int v   = bid*8 + grp;
  const int c0  = l*4;
  const int head = l >> 3;
  const int beg = rowptr[v], end = rowptr[v+1];
  float den = 0.f, o0 = 0.f, o1 = 0.f, o2 = 0.f, o3 = 0.f;
  const unsigned short* xsu = (const unsigned short*)xs;
  for (int t = beg; t < end; t++){
    float w = expal[(long)t*4 + head];
    long s = src_t[t];
    ushort4 a = *(const ushort4*)(xsu + s*128 + c0);
    den += w;
    o0 += w*b2f_raw(a.x); o1 += w*b2f_raw(a.y);
    o2 += w*b2f_raw(a.z); o3 += w*b2f_raw(a.w);
  }
  float inv = 1.f/(den + 1e-16f);
  float4 gb = *(const float4*)(gatb_f + c0);
  unsigned int lo = cvtpk_bf16(o0*inv + gb.x, o1*inv + gb.y);
  unsigned int hi = cvtpk_bf16(o2*inv + gb.z, o3*inv + gb.w);
  *(uint2*)&((unsigned short*)h_local)[(long)v*128 + c0] = (uint2){lo, hi};
}

// ---------------- MFMA flash attention (no-max softmax, scatter prefetch) ------------
__global__ __launch_bounds__(512, 6) void attn2_k(const bf16* __restrict__ qb,
    const bf16* __restrict__ kb, const bf16* __restrict__ vb,
    const float* __restrict__ ebuf_t, const unsigned short* __restrict__ epack,
    const int* __restrict__ rowptr, bf16* __restrict__ hattn){
  __shared__ short Vf[16*64*8];     // 16 KB
  __shared__ float sb[256*33];      // 33.8 KB
  const int bid = blockIdx.x;
  const int h = (bid >> 3) >> 4;
  const int g = (((bid >> 3) & 15) << 3) | (bid & 7);
  const int tid = threadIdx.x;
  const int w = tid >> 6, l = tid & 63;
  const int q31 = l & 31, hi = l >> 5;
  const int nbase = g << 8;

  for (int s2 = tid; s2 < 1024; s2 += 512){
    int f = s2 >> 6, ll = s2 & 63;
    int keyb = (f>>1)*32 + (f&1)*16 + ((ll>>5)*8);
    int d = ll & 15;
    short tmp[8];
    #pragma unroll
    for (int j=0;j<8;j++)
      tmp[j] = ((const short*)vb)[((long)(nbase + keyb + j))*128 + h*16 + d];
    *(short8*)&Vf[s2*8] = *(short8*)tmp;
  }
  for (int i = tid; i < 256*33; i += 512) sb[i] = 0.f;
  short8 qf = *(const short8*)((const short*)qb + ((long)(nbase + w*32 + q31))*128 + h*16 + hi*8);
  const float* ebh = ebuf_t + (long)h*kE;
  int rp[9];
  #pragma unroll
  for (int i=0;i<9;i++) rp[i] = rowptr[nbase + i*32];
  // prefetch tile 0's scatter data
  int tpre = rp[0] + tid;
  bool have = tpre < rp[1];
  unsigned int pp = 0; float pb = 0.f;
  if (have){ pp = epack[tpre]; pb = ebh[tpre]; }
  short8 kf = *(const short8*)((const short*)kb + ((long)(nbase + q31))*128 + h*16 + hi*8);
  __syncthreads();

  float lsum = 0.f;
  f32x16 oacc = {0.f,0.f,0.f,0.f,0.f,0.f,0.f,0.f,0.f,0.f,0.f,0.f,0.f,0.f,0.f,0.f};
  #pragma unroll 1
  for (int kt = 0; kt < 8; kt++){
    // scatter current tile's bias (prefetched; overflow handled inline)
    if (have) atomicAdd(&sb[(pp>>8)*33 + (pp&31)], pb);
    for (int t2 = rp[kt] + tid + 512; t2 < rp[kt+1]; t2 += 512){
      unsigned int p2 = epack[t2];
      atomicAdd(&sb[(p2>>8)*33 + (p2&31)], ebh[t2]);
    }
    __syncthreads();
    // prefetch next tile's scatter data (overlaps MFMA/exp/PV below)
    if (kt < 7){
      int tn = rp[kt+1] + tid;
      have = tn < rp[kt+2];
      pp = 0; pb = 0.f;
      if (have){ pp = epack[tn]; pb = ebh[tn]; }
    } else have = false;
    short8 kcur = kf;
    if (kt < 7)
      kf = *(const short8*)((const short*)kb +
            ((long)(nbase + (kt+1)*32 + q31))*128 + h*16 + hi*8);
    f32x16 acc = {0.f,0.f,0.f,0.f,0.f,0.f,0.f,0.f,0.f,0.f,0.f,0.f,0.f,0.f,0.f,0.f};
    acc = __builtin_amdgcn_mfma_f32_32x32x16_bf16(kcur, qf, acc, 0, 0, 0);
    float s[16];
    float* brow = &sb[(w*32 + q31)*33];
    #pragma unroll
    for (int r=0;r<16;r++){
      int krow = (r&3) + 8*(r>>2) + 4*hi;
      s[r] = fmaf(acc[r], 0.25f, brow[krow]);
      brow[krow] = 0.f;
    }
    __syncthreads();
    float psum = 0.f;
    #pragma unroll
    for (int r=0;r<16;r++){ s[r] = __expf(s[r]); psum += s[r]; }
    lsum += psum;
    unsigned int a  = cvtpk_bf16(s[0],  s[1]);
    unsigned int b  = cvtpk_bf16(s[2],  s[3]);
    unsigned int c  = cvtpk_bf16(s[4],  s[5]);
    unsigned int d  = cvtpk_bf16(s[6],  s[7]);
    unsigned int e  = cvtpk_bf16(s[8],  s[9]);
    unsigned int f  = cvtpk_bf16(s[10], s[11]);
    unsigned int g2 = cvtpk_bf16(s[12], s[13]);
    unsigned int h2 = cvtpk_bf16(s[14], s[15]);
    plane_swap(a, c); plane_swap(b, d); plane_swap(e, g2); plane_swap(f, h2);
    union { unsigned int u[4]; short8 s8; } A1, A2;
    A1.u[0]=a; A1.u[1]=b; A1.u[2]=c; A1.u[3]=d;
    A2.u[0]=e; A2.u[1]=f; A2.u[2]=g2; A2.u[3]=h2;
    short8 v1 = *(short8*)&Vf[((kt*2+0)*64 + l)*8];
    short8 v2 = *(short8*)&Vf[((kt*2+1)*64 + l)*8];
    oacc = __builtin_amdgcn_mfma_f32_32x32x16_bf16(A1.s8, v1, oacc, 0,0,0);
    oacc = __builtin_amdgcn_mfma_f32_32x32x16_bf16(A2.s8, v2, oacc, 0,0,0);
  }
  lsum += __shfl_xor(lsum, 32);
  float linv = 1.f / lsum;
  #pragma unroll
  for (int r=0;r<16;r++){
    int qrow = (r&3) + 8*(r>>2) + 4*hi;
    float li = __shfl(linv, qrow);
    float ov = oacc[r]*li;
    if (q31 < 16)
      hattn[((long)(nbase + w*32 + qrow))*128 + h*16 + q31] = f2b(ov);
  }
}

// =====================================================================================
extern "C" void kernel_launch(void* const* d_in, const int* in_sizes, int n_in,
                              void* d_out, int out_size, void* d_ws, size_t ws_size,
                              hipStream_t stream){
  const void* x_raw   = d_in[0];
  const void* ea_raw  = d_in[1];
  const int*  ei      = (const int*)d_in[25];
  const int* srcA = ei;
  const int* dstA = ei + kE;

  char* ws = (char*)d_ws;
  size_t off = 0;
  auto alloc = [&](size_t bytes)->void*{
    void* p = ws + off;
    off = (off + bytes + 255) & ~(size_t)255;
    return p;
  };
  int*   flag    = (int*)alloc(4);
  float* Wsrc_f  = (float*)alloc(16384*4);
  float* Wdst_f  = (float*)alloc(16384*4);
  float* Wedge_f = (float*)alloc(4096*4);
  float* att_f   = (float*)alloc(128*4);
  float* gatb_f  = (float*)alloc(128*4);
  float* Wq_f    = (float*)alloc(16384*4);
  float* Wk_f    = (float*)alloc(16384*4);
  float* Wv_f    = (float*)alloc(16384*4);
  float* Wo_f    = (float*)alloc(16384*4);
  float* bo_f    = (float*)alloc(128*4);
  float* We_f    = (float*)alloc(256*4);
  float* be_f    = (float*)alloc(8*4);
  float* ln1g_f  = (float*)alloc(128*4);
  float* ln1b_f  = (float*)alloc(128*4);
  float* W1_f    = (float*)alloc(32768*4);
  float* b1_f    = (float*)alloc(256*4);
  float* W2_f    = (float*)alloc(32768*4);
  float* b2_f    = (float*)alloc(128*4);
  float* ln2g_f  = (float*)alloc(128*4);
  float* ln2b_f  = (float*)alloc(128*4);
  float* bias5   = (float*)alloc(640*4);
  bf16*  Wrep5   = (bf16*)alloc((size_t)5*16384*2);
  bf16*  WoR     = (bf16*)alloc((size_t)16384*2);
  bf16*  W1R     = (bf16*)alloc((size_t)32768*2);
  bf16*  W2R     = (bf16*)alloc((size_t)32768*2);
  bf16*  WeR     = (bf16*)alloc((size_t)4096*2);
  bf16*  WeRb    = (bf16*)alloc((size_t)512*2);
  bf16*  proj5   = (bf16*)alloc((size_t)5*kN*128*2);
  bf16* xs   = proj5;
  bf16* xd   = proj5 + (size_t)kN*128;
  bf16* qb   = proj5 + (size_t)2*kN*128;
  bf16* kbuf = proj5 + (size_t)3*kN*128;
  bf16* vbuf = proj5 + (size_t)4*kN*128;
  int* cnt        = (int*)alloc((size_t)2*kN*4);
  int* cursor     = cnt + kN;
  int* rowptr     = (int*)alloc((size_t)(kN+1)*4);
  int* eidx       = (int*)alloc((size_t)kE*4);
  unsigned short* epack = (unsigned short*)alloc((size_t)kE*2);
  float* ebuf_t   = (float*)alloc((size_t)8*kE*4);
  float* expal_t  = (float*)alloc((size_t)kE*4*4);
  int*   src_t    = (int*)alloc((size_t)kE*4);
  bf16* h_local   = (bf16*)alloc((size_t)kN*128*2);
  bf16* hattn_pre = (bf16*)alloc((size_t)kN*128*2);
  bf16* hbuf      = (bf16*)alloc((size_t)kN*128*2);
  bf16* tbuf      = (bf16*)alloc((size_t)kN*256*2);
  (void)ws_size; (void)in_sizes; (void)n_in; (void)out_size;

  dim3 b256(256);

  detect_k<<<1, b256, 0, stream>>>(x_raw, flag);
  hipMemsetAsync(bias5, 0, 256*4, stream);
  hipMemsetAsync(cnt, 0, (size_t)2*kN*4, stream);

  // CSR by dst (edge3/gat order + attn bias scatter)
  hist_k<<<kE/256, b256, 0, stream>>>(dstA, cnt);
  scan_k<<<1, 1024, 0, stream>>>(cnt, rowptr);
  scatter_k<<<kE/256, b256, 0, stream>>>(dstA, rowptr, cursor, eidx);

  ImpArgs ia;
  const void* srcs[23] = {d_in[2], d_in[3], d_in[4], d_in[5], d_in[6],
                          d_in[7], d_in[8], d_in[9], d_in[10], d_in[11], d_in[12],
                          d_in[13], d_in[14], d_in[15], d_in[16], d_in[17], d_in[18],
                          d_in[19], d_in[20], d_in[21], d_in[22], d_in[23], d_in[24]};
  void* dsts[23] = {Wsrc_f, Wdst_f, Wedge_f, att_f, gatb_f,
                    Wq_f, bias5+256, Wk_f, bias5+384, Wv_f, bias5+512,
                    Wo_f, bo_f, We_f, be_f, ln1g_f, ln1b_f,
                    W1_f, b1_f, W2_f, b2_f, ln2g_f, ln2b_f};
  int ns[23] = {16384, 16384, 4096, 128, 128,
                16384, 128, 16384, 128, 16384, 128,
                16384, 128, 256, 8, 128, 128,
                32768, 256, 32768, 128, 128, 128};
  for (int i=0;i<23;i++){ ia.e[i].src=srcs[i]; ia.e[i].dst=dsts[i]; ia.e[i].n=ns[i]; }
  import_k<<<dim3(64,23), b256, 0, stream>>>(ia, flag);

  repack5_k<<<(5*16384)/256, b256, 0, stream>>>(Wsrc_f, Wdst_f, Wq_f, Wk_f, Wv_f, Wrep5);
  RepEnt ro{Wo_f, WoR, 16384, 3, 128, 0};
  RepEnt r1{W1_f, W1R, 32768, 4, 256, 0};
  RepEnt r2{W2_f, W2R, 32768, 3, 128, 0};
  RepEnt re{Wedge_f, WeR, 4096, 3, 128, 1};
  RepEnt rb{We_f, WeRb, 512, 0, 8, 2};
  repack_k<<<dim3(128,5), b256, 0, stream>>>(ro, r1, r2, re, rb);

  gemm5_k<<<kN/64, b256, 0, stream>>>(x_raw, flag, Wrep5, bias5, proj5);

  edge3_k<<<kE/64, b256, 0, stream>>>(ea_raw, flag, eidx, srcA, dstA, xs, xd,
                                      WeR, WeRb, att_f, be_f,
                                      expal_t, ebuf_t, epack, src_t);

  gat_agg_k<<<kN/8, b256, 0, stream>>>(expal_t, rowptr, src_t, xs, gatb_f, h_local);

  attn2_k<<<kG*kHA, dim3(512), 0, stream>>>(qb, kbuf, vbuf, ebuf_t, epack, rowptr, hattn_pre);

  // Wo GEMM + (x + h_local + h_attn) + LN1 -> hbuf (fused)
  gemm_ln_k<128,0><<<kN/64, b256, 0, stream>>>(hattn_pre, WoR, bo_f,
                                               h_local, x_raw, ln1g_f, ln1b_f,
                                               hbuf, flag);

  gemm_mfma_k<128,256,2><<<kN/64, b256, 0, stream>>>(hbuf, W1R, b1_f, tbuf);

  // W2 GEMM + (hbuf + ffn) + LN2 -> d_out (fused, dtype per flag)
  gemm_ln_k<256,1><<<kN/64, b256, 0, stream>>>(tbuf, W2R, b2_f,
                                               hbuf, nullptr, ln2g_f, ln2b_f,
                                               d_out, flag);
}

// Round 14
// 220.965 us; speedup vs baseline: 1.5384x; 1.0208x over previous
//
#include <hip/hip_runtime.h>
#include <hip/hip_bf16.h>

typedef __hip_bfloat16 bf16;
typedef __hip_bfloat162 bf162;
typedef __attribute__((ext_vector_type(8))) short short8;
typedef __attribute__((ext_vector_type(4))) float f32x4;
typedef __attribute__((ext_vector_type(16))) float f32x16;

constexpr int kN   = 32768;   // nodes
constexpr int kG   = 128;     // graphs
constexpr int kE   = 262144;  // edges
constexpr int kHA  = 8;       // global attn heads

__device__ __forceinline__ float b2f(bf16 v){ return __bfloat162float(v); }
__device__ __forceinline__ bf16  f2b(float v){ return __float2bfloat16(v); }
__device__ __forceinline__ float b2f_raw(unsigned short u){
  return __uint_as_float((unsigned)u << 16);
}
__device__ __forceinline__ float tanh_fast(float x){
  float e = __expf(2.f*x);
  return 1.f - 2.f/(e+1.f);
}
__device__ __forceinline__ unsigned int cvtpk_bf16(float lo, float hi){
  unsigned int r;
  asm volatile("v_cvt_pk_bf16_f32 %0, %1, %2" : "=v"(r) : "v"(lo), "v"(hi));
  return r;
}
__device__ __forceinline__ void plane_swap(unsigned int &a, unsigned int &b){
  asm volatile("v_permlane32_swap_b32 %0, %1" : "+v"(a), "+v"(b));
}

// ---------------- input dtype detection (bf16 vs fp32 device buffers) ----------------
__global__ void detect_k(const void* xraw, int* flag){
  const bf16* p = (const bf16*)xraw;
  int good = 0;
  for (int i = threadIdx.x; i < 4096; i += 256){
    float v = fabsf(b2f(p[i]));
    if (v > 0.0009765625f && v < 16.f) good++;
  }
  __shared__ int s[256];
  s[threadIdx.x] = good;
  __syncthreads();
  for (int d = 128; d; d >>= 1){
    if (threadIdx.x < d) s[threadIdx.x] += s[threadIdx.x + d];
    __syncthreads();
  }
  if (threadIdx.x == 0) *flag = (s[0] < 3500) ? 1 : 0;
}

// ---------------- import (params to fp32 ws) ----------------
struct ImpEnt { const void* src; void* dst; int n; };
struct ImpArgs { ImpEnt e[23]; };
__global__ __launch_bounds__(256) void import_k(ImpArgs a, const int* __restrict__ flag){
  ImpEnt en = a.e[blockIdx.y];
  const bool f32 = (*flag != 0);
  for (int i = blockIdx.x*256 + threadIdx.x; i < en.n; i += gridDim.x*256){
    float v = f32 ? ((const float*)en.src)[i] : b2f(((const bf16*)en.src)[i]);
    ((float*)en.dst)[i] = v;
  }
}

// ---------------- weight repack to MFMA-B fragment layout ----------------
__global__ __launch_bounds__(256) void repack5_k(const float* __restrict__ W0,
    const float* __restrict__ W1p, const float* __restrict__ W2p,
    const float* __restrict__ W3p, const float* __restrict__ W4p,
    bf16* __restrict__ dst){
  int idx = blockIdx.x*256 + threadIdx.x;
  const float* Ws[5] = {W0, W1p, W2p, W3p, W4p};
  int o = idx >> 14;
  int rem = idx & 16383;
  int j = rem & 7, l = (rem >> 3) & 63, t = rem >> 9;
  int ks = t >> 3, cb = t & 7;
  int k = ks*32 + (l>>4)*8 + j;
  int c = cb*16 + (l&15);
  dst[idx] = f2b(Ws[o][k*128 + c]);
}

// mode 0: plain; mode 1: perm'd cols p(c)=(c&15)*8+(c>>4); mode 2: We 32x8 padded to 16 cols
struct RepEnt { const float* src; bf16* dst; int total; int ncb_log; int dout; int mode; };
__global__ __launch_bounds__(256) void repack_k(RepEnt e0, RepEnt e1, RepEnt e2,
                                                RepEnt e3, RepEnt e4){
  RepEnt en = (blockIdx.y == 0) ? e0 : (blockIdx.y == 1) ? e1 :
              (blockIdx.y == 2) ? e2 : (blockIdx.y == 3) ? e3 : e4;
  int idx = blockIdx.x*256 + threadIdx.x;
  if (idx >= en.total) return;
  int j = idx & 7, l = (idx >> 3) & 63, t = idx >> 9;
  if (en.mode == 2){
    int k = (l>>4)*8 + j;
    int c = l & 15;
    en.dst[idx] = (c < 8) ? f2b(en.src[k*8 + c]) : f2b(0.f);
    return;
  }
  int ncbm = (1 << en.ncb_log) - 1;
  int ks = t >> en.ncb_log, cb = t & ncbm;
  int k = ks*32 + (l>>4)*8 + j;
  int c = cb*16 + (l&15);
  if (en.mode == 1) c = ((c & 15) << 3) | (c >> 4);
  en.dst[idx] = f2b(en.src[k*en.dout + c]);
}

// ---------------- fused 5-way projection GEMM (reads raw x, dtype-flag branch) -------
__global__ __launch_bounds__(256) void gemm5_k(const void* __restrict__ xraw,
    const int* __restrict__ flag,
    const bf16* __restrict__ Wrep, const float* __restrict__ bias5,
    bf16* __restrict__ proj5){
  const int tid = threadIdx.x;
  const int wid = tid >> 6, l = tid & 63;
  const long r0 = (long)blockIdx.x*64 + wid*16;
  const bool f32 = (*flag != 0);
  short8 af[4];
  if (f32){
    const float* fr = (const float*)xraw + (r0 + (l&15))*128;
    #pragma unroll
    for (int ks=0; ks<4; ks++){
      float4 a = *(const float4*)(fr + ks*32 + (l>>4)*8);
      float4 b = *(const float4*)(fr + ks*32 + (l>>4)*8 + 4);
      union{ unsigned int u[4]; short8 s; } c;
      c.u[0]=cvtpk_bf16(a.x,a.y); c.u[1]=cvtpk_bf16(a.z,a.w);
      c.u[2]=cvtpk_bf16(b.x,b.y); c.u[3]=cvtpk_bf16(b.z,b.w);
      af[ks] = c.s;
    }
  } else {
    const short* Arow = (const short*)xraw + (r0 + (l&15))*128;
    #pragma unroll
    for (int ks=0; ks<4; ks++)
      af[ks] = *(const short8*)(Arow + ks*32 + (l>>4)*8);
  }
  const short8* Wp = (const short8*)Wrep;
  const int cc = l & 15, rr = (l >> 4) * 4;
  #pragma unroll 1
  for (int o=0; o<5; o++){
    f32x4 acc[8];
    #pragma unroll
    for (int cb=0; cb<8; cb++) acc[cb] = (f32x4){0.f,0.f,0.f,0.f};
    #pragma unroll
    for (int ks=0; ks<4; ks++){
      #pragma unroll
      for (int cb=0; cb<8; cb++){
        short8 bf = Wp[(o*32 + ks*8 + cb)*64 + l];
        acc[cb] = __builtin_amdgcn_mfma_f32_16x16x32_bf16(af[ks], bf, acc[cb], 0,0,0);
      }
    }
    bf16* outb = proj5 + (long)o*kN*128;
    #pragma unroll
    for (int cb=0; cb<8; cb++){
      float bb = bias5[o*128 + cb*16 + cc];
      #pragma unroll
      for (int r=0; r<4; r++){
        long row = r0 + rr + r;
        outb[row*128 + cb*16 + cc] = f2b(acc[cb][r] + bb);
      }
    }
  }
}

// ---------------- generic MFMA GEMM ----------------
template<int DIN, int DOUT, int EPI>
__global__ __launch_bounds__(256) void gemm_mfma_k(const bf16* __restrict__ A,
    const bf16* __restrict__ Wrep, const float* __restrict__ bias,
    bf16* __restrict__ C){
  constexpr int KS = DIN/32, NCB = DOUT/16;
  const int tid = threadIdx.x;
  const int wid = tid >> 6, l = tid & 63;
  const long r0 = (long)blockIdx.x*64 + wid*16;
  const short* Arow = (const short*)(A + (r0 + (l&15))*(long)DIN);
  short8 af[KS];
  #pragma unroll
  for (int ks=0; ks<KS; ks++)
    af[ks] = *(const short8*)(Arow + ks*32 + (l>>4)*8);
  f32x4 acc[NCB];
  #pragma unroll
  for (int cb=0; cb<NCB; cb++) acc[cb] = (f32x4){0.f,0.f,0.f,0.f};
  const short8* Wp = (const short8*)Wrep;
  #pragma unroll
  for (int ks=0; ks<KS; ks++){
    #pragma unroll
    for (int cb=0; cb<NCB; cb++){
      short8 bf = Wp[(ks*NCB + cb)*64 + l];
      acc[cb] = __builtin_amdgcn_mfma_f32_16x16x32_bf16(af[ks], bf, acc[cb], 0,0,0);
    }
  }
  const int cc = l & 15, rr = (l >> 4) * 4;
  #pragma unroll
  for (int cb=0; cb<NCB; cb++){
    float bb = bias[cb*16 + cc];
    #pragma unroll
    for (int r=0; r<4; r++){
      long row = r0 + rr + r;
      float v = acc[cb][r] + bb;
      if (EPI == 2) v = 0.5f*v*(1.f + erff(v*0.70710678118654752f));
      C[row*DOUT + cb*16 + cc] = f2b(v);
    }
  }
}

// ---------------- fused MFMA GEMM + residual add + LayerNorm ----------------
template<int DIN, int FINAL>
__global__ __launch_bounds__(256) void gemm_ln_k(const bf16* __restrict__ A,
    const bf16* __restrict__ Wrep, const float* __restrict__ bias,
    const bf16* __restrict__ res1, const void* __restrict__ res2raw,
    const float* __restrict__ g, const float* __restrict__ bb,
    void* __restrict__ outp, const int* __restrict__ flag){
  constexpr int KS = DIN/32;
  const int tid = threadIdx.x;
  const int wid = tid >> 6, l = tid & 63;
  const long r0 = (long)blockIdx.x*64 + wid*16;
  const short* Arow = (const short*)(A + (r0 + (l&15))*(long)DIN);
  short8 af[KS];
  #pragma unroll
  for (int ks=0; ks<KS; ks++)
    af[ks] = *(const short8*)(Arow + ks*32 + (l>>4)*8);
  f32x4 acc[8];
  #pragma unroll
  for (int cb=0; cb<8; cb++) acc[cb] = (f32x4){0.f,0.f,0.f,0.f};
  const short8* Wp = (const short8*)Wrep;
  #pragma unroll
  for (int ks=0; ks<KS; ks++){
    #pragma unroll
    for (int cb=0; cb<8; cb++){
      short8 bf = Wp[(ks*8 + cb)*64 + l];
      acc[cb] = __builtin_amdgcn_mfma_f32_16x16x32_bf16(af[ks], bf, acc[cb], 0,0,0);
    }
  }
  const int cc = l & 15, rr = (l >> 4) * 4;
  const bool f32 = (*flag != 0);
  float v[8][4];
  #pragma unroll
  for (int cb=0; cb<8; cb++){
    float bv = bias[cb*16 + cc];
    #pragma unroll
    for (int r=0; r<4; r++){
      long row = r0 + rr + r;
      float t = acc[cb][r] + bv + b2f(res1[row*128 + cb*16 + cc]);
      if (res2raw){
        t += f32 ? ((const float*)res2raw)[row*128 + cb*16 + cc]
                 : b2f(((const bf16*)res2raw)[row*128 + cb*16 + cc]);
      }
      v[cb][r] = t;
    }
  }
  float gv[8], bbv[8];
  #pragma unroll
  for (int cb=0; cb<8; cb++){ gv[cb] = g[cb*16+cc]; bbv[cb] = bb[cb*16+cc]; }
  #pragma unroll
  for (int r=0; r<4; r++){
    float s = 0.f;
    #pragma unroll
    for (int cb=0; cb<8; cb++) s += v[cb][r];
    s += __shfl_xor(s,1); s += __shfl_xor(s,2);
    s += __shfl_xor(s,4); s += __shfl_xor(s,8);
    float mean = s * (1.f/128.f);
    float q = 0.f;
    #pragma unroll
    for (int cb=0; cb<8; cb++){ float d = v[cb][r]-mean; q += d*d; }
    q += __shfl_xor(q,1); q += __shfl_xor(q,2);
    q += __shfl_xor(q,4); q += __shfl_xor(q,8);
    float rstd = rsqrtf(q*(1.f/128.f) + 1e-5f);
    long row = r0 + rr + r;
    if (FINAL && f32){
      float* o = (float*)outp;
      #pragma unroll
      for (int cb=0; cb<8; cb++)
        o[row*128 + cb*16 + cc] = (v[cb][r]-mean)*rstd*gv[cb] + bbv[cb];
    } else {
      bf16* o = (bf16*)outp;
      #pragma unroll
      for (int cb=0; cb<8; cb++)
        o[row*128 + cb*16 + cc] = f2b((v[cb][r]-mean)*rstd*gv[cb] + bbv[cb]);
    }
  }
}

// ---------------- CSR build (parallel scan) ----------------
__global__ void hist_k(const int* __restrict__ dstA, int* __restrict__ cnt){
  int e = blockIdx.x*256 + threadIdx.x;
  if (e < kE) atomicAdd(&cnt[dstA[e]], 1);
}

// per-block (256 elems) exclusive scan + block total
__global__ __launch_bounds__(256) void blockscan_k(const int* __restrict__ cnt,
    int* __restrict__ pre, int* __restrict__ btot){
  const int b = blockIdx.x, t = threadIdx.x;
  const int i = b*256 + t;
  int v = cnt[i];
  __shared__ int s[256];
  s[t] = v;
  __syncthreads();
  for (int d = 1; d < 256; d <<= 1){
    int x = (t >= d) ? s[t-d] : 0;
    __syncthreads();
    s[t] += x;
    __syncthreads();
  }
  pre[i] = s[t] - v;
  if (t == 255) btot[b] = s[255];
}

// add block offsets (computed inline from 128 totals)
__global__ __launch_bounds__(256) void scanfix_k(const int* __restrict__ pre,
    const int* __restrict__ btot, int* __restrict__ rowptr){
  const int b = blockIdx.x, t = threadIdx.x;
  __shared__ int boff;
  if (t == 0){
    int s = 0;
    for (int i = 0; i < b; i++) s += btot[i];
    boff = s;
  }
  __syncthreads();
  rowptr[b*256 + t] = pre[b*256 + t] + boff;
  if (b == 127 && t == 255) rowptr[kN] = kE;
}

__global__ void scatter_k(const int* __restrict__ dstA, const int* __restrict__ rowptr,
                          int* __restrict__ cursor, int* __restrict__ eidx){
  int e = blockIdx.x*256 + threadIdx.x;
  if (e < kE){
    int d = dstA[e];
    int p = atomicAdd(&cursor[d], 1);
    eidx[rowptr[d]+p] = e;
  }
}

// ---------------- edge3 v4: CSR-ordered, MFMA edge GEMM (perm'd cols) + MFMA eb ------
__global__ __launch_bounds__(256) void edge3_k(const void* __restrict__ ea_raw,
    const int* __restrict__ flag,
    const int* __restrict__ eidx, const int* __restrict__ srcA,
    const int* __restrict__ dstA,
    const bf16* __restrict__ xs, const bf16* __restrict__ xd,
    const bf16* __restrict__ WeR_edge,
    const bf16* __restrict__ WeR_eb,
    const float* __restrict__ att_f, const float* __restrict__ be_f,
    float* __restrict__ expal_t, float* __restrict__ ebuf_t,
    unsigned short* __restrict__ epack, int* __restrict__ src_t){
  __shared__ int sEid[64], sSrc[64], sDst[64];
  __shared__ float sAlphaF[64*4];
  const int tid = threadIdx.x;
  const int w = tid >> 6, l = tid & 63;
  const int p = blockIdx.x;
  const int bid = (p & 7) * (gridDim.x >> 3) + (p >> 3);
  const long t0 = (long)bid * 64;
  const bool f32 = (*flag != 0);

  if (tid < 64){
    int e = eidx[t0 + tid];
    int s = srcA[e], d = dstA[e];
    sEid[tid] = e; sSrc[tid] = s; sDst[tid] = d;
    src_t[t0 + tid] = s;
    epack[t0 + tid] = (unsigned short)(((s & 255) << 8) | (d & 255));
  }
  __syncthreads();

  short8 af;
  {
    long eoff = (long)sEid[w*16 + (l&15)]*32 + (l>>4)*8;
    if (f32){
      const float* er = (const float*)ea_raw + eoff;
      float4 a = *(const float4*)er;
      float4 b = *(const float4*)(er + 4);
      union{ unsigned int u[4]; short8 s; } c;
      c.u[0]=cvtpk_bf16(a.x,a.y); c.u[1]=cvtpk_bf16(a.z,a.w);
      c.u[2]=cvtpk_bf16(b.x,b.y); c.u[3]=cvtpk_bf16(b.z,b.w);
      af = c.s;
    } else {
      af = *(const short8*)((const short*)ea_raw + eoff);
    }
  }

  f32x4 acc[8], acc_eb;
  #pragma unroll
  for (int cb=0; cb<8; cb++){
    short8 wb = *(const short8*)((const short*)WeR_edge + (cb*64 + l)*8);
    acc[cb] = __builtin_amdgcn_mfma_f32_16x16x32_bf16(af, wb,
                (f32x4){0.f,0.f,0.f,0.f}, 0,0,0);
  }
  {
    short8 wbe = *(const short8*)((const short*)WeR_eb + l*8);
    acc_eb = __builtin_amdgcn_mfma_f32_16x16x32_bf16(af, wbe,
                (f32x4){0.f,0.f,0.f,0.f}, 0,0,0);
  }

  const int c15 = l & 15;
  const float be_v = be_f[c15 & 7];
  float4 at0 = *(const float4*)(att_f + c15*8);
  float4 at1 = *(const float4*)(att_f + c15*8 + 4);
  const float attv[8] = {at0.x,at0.y,at0.z,at0.w, at1.x,at1.y,at1.z,at1.w};
  union U8 { short8 s8; unsigned short u[8]; };
  U8 gx[4], gd[4];
  #pragma unroll
  for (int r=0; r<4; r++){
    int e_l = w*16 + (l>>4)*4 + r;
    gx[r].s8 = *(const short8*)((const short*)xs + (long)sSrc[e_l]*128 + c15*8);
    gd[r].s8 = *(const short8*)((const short*)xd + (long)sDst[e_l]*128 + c15*8);
  }
  #pragma unroll
  for (int r=0; r<4; r++){
    int e_l = w*16 + (l>>4)*4 + r;
    float hsum = 0.f;
    #pragma unroll
    for (int cb=0; cb<8; cb++){
      float v = acc[cb][r] + b2f_raw(gx[r].u[cb]) + b2f_raw(gd[r].u[cb]);
      hsum += tanh_fast(v) * attv[cb];
    }
    hsum += __shfl_xor(hsum,1);
    hsum += __shfl_xor(hsum,2);
    if ((c15 & 3) == 0) sAlphaF[e_l*4 + (c15>>2)] = __expf(hsum);
    if (c15 < 8) ebuf_t[(long)c15*kE + t0 + e_l] = acc_eb[r] + be_v;
  }
  __syncthreads();
  if (tid < 64)
    *(float4*)&expal_t[(t0 + tid)*4] = *(float4*)&sAlphaF[tid*4];
}

// ---------------- GAT aggregate: 64 lanes/node (2-way edge split), single pass -------
__global__ __launch_bounds__(256) void gat_agg_k(const float* __restrict__ expal,
    const int* __restrict__ rowptr, const int* __restrict__ src_t,
    const bf16* __restrict__ xs, const float* __restrict__ gatb_f,
    bf16* __restrict__ h_local){
  const int tid = threadIdx.x;
  const int grp = tid >> 6;            // 4 nodes per block
  const int l   = tid & 63;
  const int half = l >> 5;
  const int l31 = l & 31;
  const int p   = blockIdx.x;
  const int bid = (p & 7) * (gridDim.x >> 3) + (p >> 3);
  const int v   = bid*4 + grp;
  const int c0  = l31*4;
  const int head = l31 >> 3;
  const int beg = rowptr[v], end = rowptr[v+1];
  const int c1 = (end - beg + 1) >> 1;          // first-half size
  const int s0 = beg + half*c1;
  const int s1 = half ? end : beg + c1;
  float den = 0.f, o0 = 0.f, o1 = 0.f, o2 = 0.f, o3 = 0.f;
  const unsigned short* xsu = (const unsigned short*)xs;
  for (int t = s0; t < s1; t++){
    float w = expal[(long)t*4 + head];
    long s = src_t[t];
    ushort4 a = *(const ushort4*)(xsu + s*128 + c0);
    den += w;
    o0 += w*b2f_raw(a.x); o1 += w*b2f_raw(a.y);
    o2 += w*b2f_raw(a.z); o3 += w*b2f_raw(a.w);
  }
  den += __shfl_xor(den, 32);
  o0 += __shfl_xor(o0, 32); o1 += __shfl_xor(o1, 32);
  o2 += __shfl_xor(o2, 32); o3 += __shfl_xor(o3, 32);
  if (half == 0){
    float inv = 1.f/(den + 1e-16f);
    float4 gb = *(const float4*)(gatb_f + c0);
    unsigned int lo = cvtpk_bf16(o0*inv + gb.x, o1*inv + gb.y);
    unsigned int hi = cvtpk_bf16(o2*inv + gb.z, o3*inv + gb.w);
    *(uint2*)&((unsigned short*)h_local)[(long)v*128 + c0] = (uint2){lo, hi};
  }
}

// ---------------- MFMA flash attention (no-max softmax, scatter prefetch) ------------
__global__ __launch_bounds__(512, 6) void attn2_k(const bf16* __restrict__ qb,
    const bf16* __restrict__ kb, const bf16* __restrict__ vb,
    const float* __restrict__ ebuf_t, const unsigned short* __restrict__ epack,
    const int* __restrict__ rowptr, bf16* __restrict__ hattn){
  __shared__ short Vf[16*64*8];     // 16 KB
  __shared__ float sb[256*33];      // 33.8 KB
  const int bid = blockIdx.x;
  const int h = (bid >> 3) >> 4;
  const int g = (((bid >> 3) & 15) << 3) | (bid & 7);
  const int tid = threadIdx.x;
  const int w = tid >> 6, l = tid & 63;
  const int q31 = l & 31, hi = l >> 5;
  const int nbase = g << 8;

  for (int s2 = tid; s2 < 1024; s2 += 512){
    int f = s2 >> 6, ll = s2 & 63;
    int keyb = (f>>1)*32 + (f&1)*16 + ((ll>>5)*8);
    int d = ll & 15;
    short tmp[8];
    #pragma unroll
    for (int j=0;j<8;j++)
      tmp[j] = ((const short*)vb)[((long)(nbase + keyb + j))*128 + h*16 + d];
    *(short8*)&Vf[s2*8] = *(short8*)tmp;
  }
  for (int i = tid; i < 256*33; i += 512) sb[i] = 0.f;
  short8 qf = *(const short8*)((const short*)qb + ((long)(nbase + w*32 + q31))*128 + h*16 + hi*8);
  const float* ebh = ebuf_t + (long)h*kE;
  int rp[9];
  #pragma unroll
  for (int i=0;i<9;i++) rp[i] = rowptr[nbase + i*32];
  int tpre = rp[0] + tid;
  bool have = tpre < rp[1];
  unsigned int pp = 0; float pb = 0.f;
  if (have){ pp = epack[tpre]; pb = ebh[tpre]; }
  short8 kf = *(const short8*)((const short*)kb + ((long)(nbase + q31))*128 + h*16 + hi*8);
  __syncthreads();

  float lsum = 0.f;
  f32x16 oacc = {0.f,0.f,0.f,0.f,0.f,0.f,0.f,0.f,0.f,0.f,0.f,0.f,0.f,0.f,0.f,0.f};
  #pragma unroll 1
  for (int kt = 0; kt < 8; kt++){
    if (have) atomicAdd(&sb[(pp>>8)*33 + (pp&31)], pb);
    for (int t2 = rp[kt] + tid + 512; t2 < rp[kt+1]; t2 += 512){
      unsigned int p2 = epack[t2];
      atomicAdd(&sb[(p2>>8)*33 + (p2&31)], ebh[t2]);
    }
    __syncthreads();
    if (kt < 7){
      int tn = rp[kt+1] + tid;
      have = tn < rp[kt+2];
      pp = 0; pb = 0.f;
      if (have){ pp = epack[tn]; pb = ebh[tn]; }
    } else have = false;
    short8 kcur = kf;
    if (kt < 7)
      kf = *(const short8*)((const short*)kb +
            ((long)(nbase + (kt+1)*32 + q31))*128 + h*16 + hi*8);
    f32x16 acc = {0.f,0.f,0.f,0.f,0.f,0.f,0.f,0.f,0.f,0.f,0.f,0.f,0.f,0.f,0.f,0.f};
    acc = __builtin_amdgcn_mfma_f32_32x32x16_bf16(kcur, qf, acc, 0, 0, 0);
    float s[16];
    float* brow = &sb[(w*32 + q31)*33];
    #pragma unroll
    for (int r=0;r<16;r++){
      int krow = (r&3) + 8*(r>>2) + 4*hi;
      s[r] = fmaf(acc[r], 0.25f, brow[krow]);
      brow[krow] = 0.f;
    }
    __syncthreads();
    float psum = 0.f;
    #pragma unroll
    for (int r=0;r<16;r++){ s[r] = __expf(s[r]); psum += s[r]; }
    lsum += psum;
    unsigned int a  = cvtpk_bf16(s[0],  s[1]);
    unsigned int b  = cvtpk_bf16(s[2],  s[3]);
    unsigned int c  = cvtpk_bf16(s[4],  s[5]);
    unsigned int d  = cvtpk_bf16(s[6],  s[7]);
    unsigned int e  = cvtpk_bf16(s[8],  s[9]);
    unsigned int f  = cvtpk_bf16(s[10], s[11]);
    unsigned int g2 = cvtpk_bf16(s[12], s[13]);
    unsigned int h2 = cvtpk_bf16(s[14], s[15]);
    plane_swap(a, c); plane_swap(b, d); plane_swap(e, g2); plane_swap(f, h2);
    union { unsigned int u[4]; short8 s8; } A1, A2;
    A1.u[0]=a; A1.u[1]=b; A1.u[2]=c; A1.u[3]=d;
    A2.u[0]=e; A2.u[1]=f; A2.u[2]=g2; A2.u[3]=h2;
    short8 v1 = *(short8*)&Vf[((kt*2+0)*64 + l)*8];
    short8 v2 = *(short8*)&Vf[((kt*2+1)*64 + l)*8];
    oacc = __builtin_amdgcn_mfma_f32_32x32x16_bf16(A1.s8, v1, oacc, 0,0,0);
    oacc = __builtin_amdgcn_mfma_f32_32x32x16_bf16(A2.s8, v2, oacc, 0,0,0);
  }
  lsum += __shfl_xor(lsum, 32);
  float linv = 1.f / lsum;
  #pragma unroll
  for (int r=0;r<16;r++){
    int qrow = (r&3) + 8*(r>>2) + 4*hi;
    float li = __shfl(linv, qrow);
    float ov = oacc[r]*li;
    if (q31 < 16)
      hattn[((long)(nbase + w*32 + qrow))*128 + h*16 + q31] = f2b(ov);
  }
}

// =====================================================================================
extern "C" void kernel_launch(void* const* d_in, const int* in_sizes, int n_in,
                              void* d_out, int out_size, void* d_ws, size_t ws_size,
                              hipStream_t stream){
  const void* x_raw   = d_in[0];
  const void* ea_raw  = d_in[1];
  const int*  ei      = (const int*)d_in[25];
  const int* srcA = ei;
  const int* dstA = ei + kE;

  char* ws = (char*)d_ws;
  size_t off = 0;
  auto alloc = [&](size_t bytes)->void*{
    void* p = ws + off;
    off = (off + bytes + 255) & ~(size_t)255;
    return p;
  };
  int*   flag    = (int*)alloc(4);
  float* Wsrc_f  = (float*)alloc(16384*4);
  float* Wdst_f  = (float*)alloc(16384*4);
  float* Wedge_f = (float*)alloc(4096*4);
  float* att_f   = (float*)alloc(128*4);
  float* gatb_f  = (float*)alloc(128*4);
  float* Wq_f    = (float*)alloc(16384*4);
  float* Wk_f    = (float*)alloc(16384*4);
  float* Wv_f    = (float*)alloc(16384*4);
  float* Wo_f    = (float*)alloc(16384*4);
  float* bo_f    = (float*)alloc(128*4);
  float* We_f    = (float*)alloc(256*4);
  float* be_f    = (float*)alloc(8*4);
  float* ln1g_f  = (float*)alloc(128*4);
  float* ln1b_f  = (float*)alloc(128*4);
  float* W1_f    = (float*)alloc(32768*4);
  float* b1_f    = (float*)alloc(256*4);
  float* W2_f    = (float*)alloc(32768*4);
  float* b2_f    = (float*)alloc(128*4);
  float* ln2g_f  = (float*)alloc(128*4);
  float* ln2b_f  = (float*)alloc(128*4);
  float* bias5   = (float*)alloc(640*4);
  bf16*  Wrep5   = (bf16*)alloc((size_t)5*16384*2);
  bf16*  WoR     = (bf16*)alloc((size_t)16384*2);
  bf16*  W1R     = (bf16*)alloc((size_t)32768*2);
  bf16*  W2R     = (bf16*)alloc((size_t)32768*2);
  bf16*  WeR     = (bf16*)alloc((size_t)4096*2);
  bf16*  WeRb    = (bf16*)alloc((size_t)512*2);
  bf16*  proj5   = (bf16*)alloc((size_t)5*kN*128*2);
  bf16* xs   = proj5;
  bf16* xd   = proj5 + (size_t)kN*128;
  bf16* qb   = proj5 + (size_t)2*kN*128;
  bf16* kbuf = proj5 + (size_t)3*kN*128;
  bf16* vbuf = proj5 + (size_t)4*kN*128;
  int* cnt        = (int*)alloc((size_t)2*kN*4);
  int* cursor     = cnt + kN;
  int* rowptr     = (int*)alloc((size_t)(kN+1)*4);
  int* pre        = (int*)alloc((size_t)kN*4);
  int* btot       = (int*)alloc((size_t)128*4);
  int* eidx       = (int*)alloc((size_t)kE*4);
  unsigned short* epack = (unsigned short*)alloc((size_t)kE*2);
  float* ebuf_t   = (float*)alloc((size_t)8*kE*4);
  float* expal_t  = (float*)alloc((size_t)kE*4*4);
  int*   src_t    = (int*)alloc((size_t)kE*4);
  bf16* h_local   = (bf16*)alloc((size_t)kN*128*2);
  bf16* hattn_pre = (bf16*)alloc((size_t)kN*128*2);
  bf16* hbuf      = (bf16*)alloc((size_t)kN*128*2);
  bf16* tbuf      = (bf16*)alloc((size_t)kN*256*2);
  (void)ws_size; (void)in_sizes; (void)n_in; (void)out_size;

  dim3 b256(256);

  detect_k<<<1, b256, 0, stream>>>(x_raw, flag);
  hipMemsetAsync(bias5, 0, 256*4, stream);
  hipMemsetAsync(cnt, 0, (size_t)2*kN*4, stream);

  // CSR by dst (parallel scan)
  hist_k<<<kE/256, b256, 0, stream>>>(dstA, cnt);
  blockscan_k<<<kN/256, b256, 0, stream>>>(cnt, pre, btot);
  scanfix_k<<<kN/256, b256, 0, stream>>>(pre, btot, rowptr);
  scatter_k<<<kE/256, b256, 0, stream>>>(dstA, rowptr, cursor, eidx);

  ImpArgs ia;
  const void* srcs[23] = {d_in[2], d_in[3], d_in[4], d_in[5], d_in[6],
                          d_in[7], d_in[8], d_in[9], d_in[10], d_in[11], d_in[12],
                          d_in[13], d_in[14], d_in[15], d_in[16], d_in[17], d_in[18],
                          d_in[19], d_in[20], d_in[21], d_in[22], d_in[23], d_in[24]};
  void* dsts[23] = {Wsrc_f, Wdst_f, Wedge_f, att_f, gatb_f,
                    Wq_f, bias5+256, Wk_f, bias5+384, Wv_f, bias5+512,
                    Wo_f, bo_f, We_f, be_f, ln1g_f, ln1b_f,
                    W1_f, b1_f, W2_f, b2_f, ln2g_f, ln2b_f};
  int ns[23] = {16384, 16384, 4096, 128, 128,
                16384, 128, 16384, 128, 16384, 128,
                16384, 128, 256, 8, 128, 128,
                32768, 256, 32768, 128, 128, 128};
  for (int i=0;i<23;i++){ ia.e[i].src=srcs[i]; ia.e[i].dst=dsts[i]; ia.e[i].n=ns[i]; }
  import_k<<<dim3(64,23), b256, 0, stream>>>(ia, flag);

  repack5_k<<<(5*16384)/256, b256, 0, stream>>>(Wsrc_f, Wdst_f, Wq_f, Wk_f, Wv_f, Wrep5);
  RepEnt ro{Wo_f, WoR, 16384, 3, 128, 0};
  RepEnt r1{W1_f, W1R, 32768, 4, 256, 0};
  RepEnt r2{W2_f, W2R, 32768, 3, 128, 0};
  RepEnt re{Wedge_f, WeR, 4096, 3, 128, 1};
  RepEnt rb{We_f, WeRb, 512, 0, 8, 2};
  repack_k<<<dim3(128,5), b256, 0, stream>>>(ro, r1, r2, re, rb);

  gemm5_k<<<kN/64, b256, 0, stream>>>(x_raw, flag, Wrep5, bias5, proj5);

  edge3_k<<<kE/64, b256, 0, stream>>>(ea_raw, flag, eidx, srcA, dstA, xs, xd,
                                      WeR, WeRb, att_f, be_f,
                                      expal_t, ebuf_t, epack, src_t);

  gat_agg_k<<<kN/4, b256, 0, stream>>>(expal_t, rowptr, src_t, xs, gatb_f, h_local);

  attn2_k<<<kG*kHA, dim3(512), 0, stream>>>(qb, kbuf, vbuf, ebuf_t, epack, rowptr, hattn_pre);

  // Wo GEMM + (x + h_local + h_attn) + LN1 -> hbuf (fused)
  gemm_ln_k<128,0><<<kN/64, b256, 0, stream>>>(hattn_pre, WoR, bo_f,
                                               h_local, x_raw, ln1g_f, ln1b_f,
                                               hbuf, flag);

  gemm_mfma_k<128,256,2><<<kN/64, b256, 0, stream>>>(hbuf, W1R, b1_f, tbuf);

  // W2 GEMM + (hbuf + ffn) + LN2 -> d_out (fused, dtype per flag)
  gemm_ln_k<256,1><<<kN/64, b256, 0, stream>>>(tbuf, W2R, b2_f,
                                               hbuf, nullptr, ln2g_f, ln2b_f,
                                               d_out, flag);
}